// Round 1
// baseline (589.127 us; speedup 1.0000x reference)
//
#include <hip/hip_runtime.h>
#include <hip/hip_bf16.h>
#include <stdint.h>

#define B_ 4
#define T_ 256
#define U_ 128
#define EH_ 1024
#define PH_ 640
#define JH_ 640
#define V_ 1024

typedef short bf16x8 __attribute__((ext_vector_type(8)));
typedef float f32x4 __attribute__((ext_vector_type(4)));
typedef unsigned short u16;

typedef const __attribute__((address_space(1))) uint32_t cgu32_t;
typedef __attribute__((address_space(3))) uint32_t lu32_t;

__device__ __forceinline__ u16 f2bf(float f) {
  union { float f; uint32_t u; } v;
  v.f = f;
  uint32_t u = v.u;
  return (u16)((u + 0x7FFFu + ((u >> 16) & 1u)) >> 16);
}

__device__ __forceinline__ void gload16(const void* g, void* l) {
  __builtin_amdgcn_global_load_lds((cgu32_t*)g, (lu32_t*)l, 16, 0, 0);
}

// ---------------------------------------------------------------------------
// Transpose + fp32->bf16: in [batch][H][W] -> out [batch][W][H]
// ---------------------------------------------------------------------------
__global__ void k_transpose_cvt(const float* __restrict__ in, u16* __restrict__ out,
                                int H, int W) {
  __shared__ float tile[32][33];
  int b = blockIdx.z;
  int h0 = blockIdx.y * 32, w0 = blockIdx.x * 32;
  const float* pin = in + (size_t)b * H * W;
  u16* pout = out + (size_t)b * H * W;
  int lw = threadIdx.x & 31, lh = threadIdx.x >> 5;
#pragma unroll
  for (int i = 0; i < 4; i++) {
    int h = lh + i * 8;
    tile[h][lw] = pin[(size_t)(h0 + h) * W + (w0 + lw)];
  }
  __syncthreads();
#pragma unroll
  for (int i = 0; i < 4; i++) {
    int w = lh + i * 8;
    pout[(size_t)(w0 + w) * H + (h0 + lw)] = f2bf(tile[lw][w]);
  }
}

// ---------------------------------------------------------------------------
// Flat fp32 -> bf16 convert (n divisible by 4)
// ---------------------------------------------------------------------------
__global__ void k_cvt_bf16(const float* __restrict__ in, u16* __restrict__ out, int n) {
  int i = blockIdx.x * blockDim.x + threadIdx.x;
  int idx = i * 4;
  if (idx < n) {
    float4 v = *(const float4*)(in + idx);
    ushort4 o;
    o.x = f2bf(v.x); o.y = f2bf(v.y); o.z = f2bf(v.z); o.w = f2bf(v.w);
    *(ushort4*)(out + idx) = o;
  }
}

// ---------------------------------------------------------------------------
// Projection GEMM: C[m][n] = sum_k A[m][k]*Bm[n][k] + bias[n]
// A bf16 [M][K] (per-batch stride), Bm bf16 [N][K], C fp32 [M][N] (per-batch)
// 64x64 tile, BK=64, 256 threads = 4 waves (2x2, each 32x32)
// ---------------------------------------------------------------------------
__global__ void k_proj_gemm(const u16* __restrict__ A, const u16* __restrict__ Bm,
                            const float* __restrict__ bias, float* __restrict__ C,
                            int K, int N, size_t strideA, size_t strideC) {
  __shared__ __align__(16) u16 sA[64 * 64];
  __shared__ __align__(16) u16 sB[64 * 64];
  int bb = blockIdx.z;
  const u16* Ab = A + (size_t)bb * strideA;
  float* Cb = C + (size_t)bb * strideC;
  int m0 = blockIdx.x * 64, n0 = blockIdx.y * 64;
  int tid = threadIdx.x;
  int lane = tid & 63, wid = tid >> 6;

  f32x4 acc[2][2] = {};
  for (int kk = 0; kk < K; kk += 64) {
#pragma unroll
    for (int i = 0; i < 2; i++) {
      int c = tid + i * 256;
      int r = c >> 3, kc = c & 7;
      int s = (r << 3) | (kc ^ (r & 7));
      *(bf16x8*)(sA + s * 8) = *(const bf16x8*)(Ab + (size_t)(m0 + r) * K + kk + kc * 8);
      *(bf16x8*)(sB + s * 8) = *(const bf16x8*)(Bm + (size_t)(n0 + r) * K + kk + kc * 8);
    }
    __syncthreads();
    int wr = (wid >> 1) * 32, wc = (wid & 1) * 32;
    int lr = lane & 15, lk = lane >> 4;
#pragma unroll
    for (int ki = 0; ki < 2; ki++) {
      bf16x8 af[2], bq[2];
#pragma unroll
      for (int mf = 0; mf < 2; mf++) {
        int r = wr + mf * 16 + lr;
        int kc = ki * 4 + lk;
        int s = (r << 3) | (kc ^ (r & 7));
        af[mf] = *(const bf16x8*)(sA + s * 8);
      }
#pragma unroll
      for (int nf = 0; nf < 2; nf++) {
        int r = wc + nf * 16 + lr;
        int kc = ki * 4 + lk;
        int s = (r << 3) | (kc ^ (r & 7));
        bq[nf] = *(const bf16x8*)(sB + s * 8);
      }
#pragma unroll
      for (int mf = 0; mf < 2; mf++)
#pragma unroll
        for (int nf = 0; nf < 2; nf++)
          acc[mf][nf] = __builtin_amdgcn_mfma_f32_16x16x32_bf16(af[mf], bq[nf], acc[mf][nf], 0, 0, 0);
    }
    __syncthreads();
  }
  int wr = (wid >> 1) * 32, wc = (wid & 1) * 32;
  int lr = lane & 15, lq = lane >> 4;
#pragma unroll
  for (int nf = 0; nf < 2; nf++) {
    int n = n0 + wc + nf * 16 + lr;
    float bv = bias[n];
#pragma unroll
    for (int mf = 0; mf < 2; mf++) {
#pragma unroll
      for (int r = 0; r < 4; r++) {
        int m = m0 + wr + mf * 16 + lq * 4 + r;
        Cb[(size_t)m * N + n] = acc[mf][nf][r] + bv;
      }
    }
  }
}

// ---------------------------------------------------------------------------
// Main fused joint GEMM: logits[b,t,u,v] = relu(e[b,t,:]+p[b,u,:]) . Wout[v,:] + bout[v]
// grid.x = b*T + t (m-tile of 128 rows == all u), grid.y = v-tile (128)
// 256 threads = 4 waves (2x2, each 64x64). BK=64, K=640 (10 steps).
// ---------------------------------------------------------------------------
__global__ void k_joint_gemm(const float* __restrict__ e, const float* __restrict__ p,
                             const u16* __restrict__ Wout, const float* __restrict__ bout,
                             float* __restrict__ out) {
  __shared__ __align__(16) u16 sH[128 * 64];
  __shared__ __align__(16) u16 sW[128 * 64];
  __shared__ __align__(16) float sE[JH_];
  int bidm = blockIdx.x;           // b*256 + t
  int n0 = blockIdx.y * 128;
  int b = bidm >> 8;
  const float* erow = e + (size_t)bidm * JH_;   // [B*T][JH]
  const float* pb = p + (size_t)b * U_ * JH_;
  int tid = threadIdx.x, lane = tid & 63, wid = tid >> 6;

  for (int i = tid; i < JH_; i += 256) sE[i] = erow[i];
  __syncthreads();

  f32x4 acc[4][4] = {};
  for (int kk = 0; kk < JH_; kk += 64) {
    // ---- stage Wout tile [128][64] via global_load_lds (linear dest, pre-swizzled src)
#pragma unroll
    for (int i = 0; i < 4; i++) {
      int cbase = wid * 256 + i * 64;
      int c = cbase + lane;
      int r = c >> 3;
      int kc = (c & 7) ^ (r & 7);
      gload16(Wout + (size_t)(n0 + r) * JH_ + kk + kc * 8, sW + (size_t)cbase * 8);
    }
    // ---- stage H tile [128][64] = relu(e_row + p) -> bf16, swizzled
#pragma unroll
    for (int i = 0; i < 4; i++) {
      int c = tid + i * 256;
      int u = c >> 3, kc = c & 7;
      int kcol = kk + kc * 8;
      const float* pp = pb + (size_t)u * JH_;
      float4 pa = *(const float4*)(pp + kcol);
      float4 pb2 = *(const float4*)(pp + kcol + 4);
      float4 ea = *(const float4*)(sE + kcol);
      float4 eb = *(const float4*)(sE + kcol + 4);
      bf16x8 hv;
      hv[0] = (short)f2bf(fmaxf(pa.x + ea.x, 0.f));
      hv[1] = (short)f2bf(fmaxf(pa.y + ea.y, 0.f));
      hv[2] = (short)f2bf(fmaxf(pa.z + ea.z, 0.f));
      hv[3] = (short)f2bf(fmaxf(pa.w + ea.w, 0.f));
      hv[4] = (short)f2bf(fmaxf(pb2.x + eb.x, 0.f));
      hv[5] = (short)f2bf(fmaxf(pb2.y + eb.y, 0.f));
      hv[6] = (short)f2bf(fmaxf(pb2.z + eb.z, 0.f));
      hv[7] = (short)f2bf(fmaxf(pb2.w + eb.w, 0.f));
      int s = (u << 3) | (kc ^ (u & 7));
      *(bf16x8*)(sH + s * 8) = hv;
    }
    __syncthreads();   // drains vmcnt for global_load_lds too
    int wr = (wid >> 1) * 64, wc = (wid & 1) * 64;
    int lr = lane & 15, lk = lane >> 4;
#pragma unroll
    for (int ki = 0; ki < 2; ki++) {
      bf16x8 af[4], bq[4];
#pragma unroll
      for (int mf = 0; mf < 4; mf++) {
        int r = wr + mf * 16 + lr;
        int kc = ki * 4 + lk;
        int s = (r << 3) | (kc ^ (r & 7));
        af[mf] = *(const bf16x8*)(sH + s * 8);
      }
#pragma unroll
      for (int nf = 0; nf < 4; nf++) {
        int r = wc + nf * 16 + lr;
        int kc = ki * 4 + lk;
        int s = (r << 3) | (kc ^ (r & 7));
        bq[nf] = *(const bf16x8*)(sW + s * 8);
      }
#pragma unroll
      for (int mf = 0; mf < 4; mf++)
#pragma unroll
        for (int nf = 0; nf < 4; nf++)
          acc[mf][nf] = __builtin_amdgcn_mfma_f32_16x16x32_bf16(af[mf], bq[nf], acc[mf][nf], 0, 0, 0);
    }
    __syncthreads();
  }
  // ---- epilogue: logits + bias -> d_out
  int wr = (wid >> 1) * 64, wc = (wid & 1) * 64;
  int lr = lane & 15, lq = lane >> 4;
  float* orow = out + (size_t)bidm * U_ * V_;
#pragma unroll
  for (int nf = 0; nf < 4; nf++) {
    int n = n0 + wc + nf * 16 + lr;
    float bv = bout[n];
#pragma unroll
    for (int mf = 0; mf < 4; mf++) {
#pragma unroll
      for (int r = 0; r < 4; r++) {
        int u = wr + mf * 16 + lq * 4 + r;
        orow[(size_t)u * V_ + n] = acc[mf][nf][r] + bv;
      }
    }
  }
}

// ---------------------------------------------------------------------------
// In-place log_softmax over last dim (V=1024), one wave per row
// ---------------------------------------------------------------------------
__global__ void k_logsoftmax(float* __restrict__ out) {
  int row = blockIdx.x * 4 + (threadIdx.x >> 6);
  int lane = threadIdx.x & 63;
  float* pr = out + (size_t)row * V_;
  float4 v[4];
  float mx = -1e30f;
#pragma unroll
  for (int i = 0; i < 4; i++) {
    v[i] = *(const float4*)(pr + (lane + i * 64) * 4);
    mx = fmaxf(mx, fmaxf(fmaxf(v[i].x, v[i].y), fmaxf(v[i].z, v[i].w)));
  }
#pragma unroll
  for (int o = 32; o > 0; o >>= 1) mx = fmaxf(mx, __shfl_xor(mx, o, 64));
  float s = 0.f;
#pragma unroll
  for (int i = 0; i < 4; i++) {
    s += __expf(v[i].x - mx) + __expf(v[i].y - mx) +
         __expf(v[i].z - mx) + __expf(v[i].w - mx);
  }
#pragma unroll
  for (int o = 32; o > 0; o >>= 1) s += __shfl_xor(s, o, 64);
  float lse = mx + __logf(s);
#pragma unroll
  for (int i = 0; i < 4; i++) {
    float4 w;
    w.x = v[i].x - lse; w.y = v[i].y - lse; w.z = v[i].z - lse; w.w = v[i].w - lse;
    *(float4*)(pr + (lane + i * 64) * 4) = w;
  }
}

// ---------------------------------------------------------------------------
extern "C" void kernel_launch(void* const* d_in, const int* in_sizes, int n_in,
                              void* d_out, int out_size, void* d_ws, size_t ws_size,
                              hipStream_t stream) {
  const float* enc    = (const float*)d_in[0];
  const float* dec    = (const float*)d_in[1];
  const float* W_enc  = (const float*)d_in[2];
  const float* b_enc  = (const float*)d_in[3];
  const float* W_pred = (const float*)d_in[4];
  const float* b_pred = (const float*)d_in[5];
  const float* W_out  = (const float*)d_in[6];
  const float* b_out  = (const float*)d_in[7];
  float* out = (float*)d_out;

  char* ws = (char*)d_ws;
  size_t off = 0;
  auto alloc = [&](size_t bytes) {
    void* pp = ws + off;
    off = (off + bytes + 255) & ~(size_t)255;
    return pp;
  };
  u16* encT   = (u16*)alloc((size_t)B_ * T_ * EH_ * 2);   // [B][T][EH] bf16
  u16* decT   = (u16*)alloc((size_t)B_ * U_ * PH_ * 2);   // [B][U][PH] bf16
  u16* WencB  = (u16*)alloc((size_t)JH_ * EH_ * 2);
  u16* WpredB = (u16*)alloc((size_t)JH_ * PH_ * 2);
  u16* WoutB  = (u16*)alloc((size_t)V_ * JH_ * 2);
  float* eBuf = (float*)alloc((size_t)B_ * T_ * JH_ * 4); // [B*T][JH]
  float* pBuf = (float*)alloc((size_t)B_ * U_ * JH_ * 4); // [B][U][JH]

  // 1) transpose+cvt enc/dec
  k_transpose_cvt<<<dim3(T_ / 32, EH_ / 32, B_), 256, 0, stream>>>(enc, encT, EH_, T_);
  k_transpose_cvt<<<dim3(U_ / 32, PH_ / 32, B_), 256, 0, stream>>>(dec, decT, PH_, U_);
  // 2) weights -> bf16
  k_cvt_bf16<<<(JH_ * EH_ / 4 + 255) / 256, 256, 0, stream>>>(W_enc, WencB, JH_ * EH_);
  k_cvt_bf16<<<(JH_ * PH_ / 4 + 255) / 256, 256, 0, stream>>>(W_pred, WpredB, JH_ * PH_);
  k_cvt_bf16<<<(V_ * JH_ / 4 + 255) / 256, 256, 0, stream>>>(W_out, WoutB, V_ * JH_);
  // 3) projections (fp32 out + bias)
  k_proj_gemm<<<dim3(T_ / 64, JH_ / 64, B_), 256, 0, stream>>>(
      encT, WencB, b_enc, eBuf, EH_, JH_, (size_t)T_ * EH_, (size_t)T_ * JH_);
  k_proj_gemm<<<dim3(U_ / 64, JH_ / 64, B_), 256, 0, stream>>>(
      decT, WpredB, b_pred, pBuf, PH_, JH_, (size_t)U_ * PH_, (size_t)U_ * JH_);
  // 4) fused joint GEMM -> logits in d_out
  k_joint_gemm<<<dim3(B_ * T_, V_ / 128), 256, 0, stream>>>(eBuf, pBuf, WoutB, b_out, out);
  // 5) in-place log_softmax
  k_logsoftmax<<<(B_ * T_ * U_) / 4, 256, 0, stream>>>(out);
}

// Round 2
// 457.683 us; speedup vs baseline: 1.2872x; 1.2872x over previous
//
#include <hip/hip_runtime.h>
#include <hip/hip_bf16.h>
#include <stdint.h>

#define B_ 4
#define T_ 256
#define U_ 128
#define EH_ 1024
#define PH_ 640
#define JH_ 640
#define V_ 1024

typedef short bf16x8 __attribute__((ext_vector_type(8)));
typedef float f32x4 __attribute__((ext_vector_type(4)));
typedef unsigned short u16;

typedef const __attribute__((address_space(1))) uint32_t cgu32_t;
typedef __attribute__((address_space(3))) uint32_t lu32_t;

__device__ __forceinline__ u16 f2bf(float f) {
  union { float f; uint32_t u; } v;
  v.f = f;
  uint32_t u = v.u;
  return (u16)((u + 0x7FFFu + ((u >> 16) & 1u)) >> 16);
}

__device__ __forceinline__ float bf2f(u16 x) {
  union { uint32_t u; float f; } v;
  v.u = (uint32_t)x << 16;
  return v.f;
}

__device__ __forceinline__ void gload16(const void* g, void* l) {
  __builtin_amdgcn_global_load_lds((cgu32_t*)g, (lu32_t*)l, 16, 0, 0);
}

// ---------------------------------------------------------------------------
// Transpose + fp32->bf16: in [batch][H][W] -> out [batch][W][H]
// ---------------------------------------------------------------------------
__global__ void k_transpose_cvt(const float* __restrict__ in, u16* __restrict__ out,
                                int H, int W) {
  __shared__ float tile[32][33];
  int b = blockIdx.z;
  int h0 = blockIdx.y * 32, w0 = blockIdx.x * 32;
  const float* pin = in + (size_t)b * H * W;
  u16* pout = out + (size_t)b * H * W;
  int lw = threadIdx.x & 31, lh = threadIdx.x >> 5;
#pragma unroll
  for (int i = 0; i < 4; i++) {
    int h = lh + i * 8;
    tile[h][lw] = pin[(size_t)(h0 + h) * W + (w0 + lw)];
  }
  __syncthreads();
#pragma unroll
  for (int i = 0; i < 4; i++) {
    int w = lh + i * 8;
    pout[(size_t)(w0 + w) * H + (h0 + lw)] = f2bf(tile[lw][w]);
  }
}

// ---------------------------------------------------------------------------
// Flat fp32 -> bf16 convert (n divisible by 4)
// ---------------------------------------------------------------------------
__global__ void k_cvt_bf16(const float* __restrict__ in, u16* __restrict__ out, int n) {
  int i = blockIdx.x * blockDim.x + threadIdx.x;
  int idx = i * 4;
  if (idx < n) {
    float4 v = *(const float4*)(in + idx);
    ushort4 o;
    o.x = f2bf(v.x); o.y = f2bf(v.y); o.z = f2bf(v.z); o.w = f2bf(v.w);
    *(ushort4*)(out + idx) = o;
  }
}

// ---------------------------------------------------------------------------
// Projection GEMM: C[m][n] = sum_k A[m][k]*Bm[n][k] + bias[n]
// ---------------------------------------------------------------------------
__global__ void k_proj_gemm(const u16* __restrict__ A, const u16* __restrict__ Bm,
                            const float* __restrict__ bias, float* __restrict__ C,
                            int K, int N, size_t strideA, size_t strideC) {
  __shared__ __align__(16) u16 sA[64 * 64];
  __shared__ __align__(16) u16 sB[64 * 64];
  int bb = blockIdx.z;
  const u16* Ab = A + (size_t)bb * strideA;
  float* Cb = C + (size_t)bb * strideC;
  int m0 = blockIdx.x * 64, n0 = blockIdx.y * 64;
  int tid = threadIdx.x;
  int lane = tid & 63, wid = tid >> 6;

  f32x4 acc[2][2] = {};
  for (int kk = 0; kk < K; kk += 64) {
#pragma unroll
    for (int i = 0; i < 2; i++) {
      int c = tid + i * 256;
      int r = c >> 3, kc = c & 7;
      int s = (r << 3) | (kc ^ (r & 7));
      *(bf16x8*)(sA + s * 8) = *(const bf16x8*)(Ab + (size_t)(m0 + r) * K + kk + kc * 8);
      *(bf16x8*)(sB + s * 8) = *(const bf16x8*)(Bm + (size_t)(n0 + r) * K + kk + kc * 8);
    }
    __syncthreads();
    int wr = (wid >> 1) * 32, wc = (wid & 1) * 32;
    int lr = lane & 15, lk = lane >> 4;
#pragma unroll
    for (int ki = 0; ki < 2; ki++) {
      bf16x8 af[2], bq[2];
#pragma unroll
      for (int mf = 0; mf < 2; mf++) {
        int r = wr + mf * 16 + lr;
        int kc = ki * 4 + lk;
        int s = (r << 3) | (kc ^ (r & 7));
        af[mf] = *(const bf16x8*)(sA + s * 8);
      }
#pragma unroll
      for (int nf = 0; nf < 2; nf++) {
        int r = wc + nf * 16 + lr;
        int kc = ki * 4 + lk;
        int s = (r << 3) | (kc ^ (r & 7));
        bq[nf] = *(const bf16x8*)(sB + s * 8);
      }
#pragma unroll
      for (int mf = 0; mf < 2; mf++)
#pragma unroll
        for (int nf = 0; nf < 2; nf++)
          acc[mf][nf] = __builtin_amdgcn_mfma_f32_16x16x32_bf16(af[mf], bq[nf], acc[mf][nf], 0, 0, 0);
    }
    __syncthreads();
  }
  int wr = (wid >> 1) * 32, wc = (wid & 1) * 32;
  int lr = lane & 15, lq = lane >> 4;
#pragma unroll
  for (int nf = 0; nf < 2; nf++) {
    int n = n0 + wc + nf * 16 + lr;
    float bv = bias[n];
#pragma unroll
    for (int mf = 0; mf < 2; mf++) {
#pragma unroll
      for (int r = 0; r < 4; r++) {
        int m = m0 + wr + mf * 16 + lq * 4 + r;
        Cb[(size_t)m * N + n] = acc[mf][nf][r] + bv;
      }
    }
  }
}

// ---------------------------------------------------------------------------
// H materialization: hB[((b*T+t)*U+u)][k] = bf16(relu(e[b,t,k] + p[b,u,k]))
// one block per (b,t); 256 threads
// ---------------------------------------------------------------------------
__global__ void k_hbuild(const float* __restrict__ e, const float* __restrict__ p,
                         u16* __restrict__ hB) {
  __shared__ __align__(16) float sE[JH_];
  int bidm = blockIdx.x;            // b*T + t
  int b = bidm >> 8;
  const float* erow = e + (size_t)bidm * JH_;
  const float* pb = p + (size_t)b * U_ * JH_;
  u16* hrow = hB + (size_t)bidm * U_ * JH_;
  int tid = threadIdx.x;
  for (int i = tid; i < JH_; i += 256) sE[i] = erow[i];
  __syncthreads();
#pragma unroll
  for (int it = 0; it < 40; it++) {
    int g = it * 256 + tid;         // 0..10239 ; 80 groups of 8 per u-row
    int u = g / 80;
    int kc = g - u * 80;
    int kcol = kc * 8;
    const float* pp = pb + (size_t)u * JH_ + kcol;
    float4 pa = *(const float4*)(pp);
    float4 pb2 = *(const float4*)(pp + 4);
    float4 ea = *(const float4*)(sE + kcol);
    float4 eb = *(const float4*)(sE + kcol + 4);
    bf16x8 hv;
    hv[0] = (short)f2bf(fmaxf(pa.x + ea.x, 0.f));
    hv[1] = (short)f2bf(fmaxf(pa.y + ea.y, 0.f));
    hv[2] = (short)f2bf(fmaxf(pa.z + ea.z, 0.f));
    hv[3] = (short)f2bf(fmaxf(pa.w + ea.w, 0.f));
    hv[4] = (short)f2bf(fmaxf(pb2.x + eb.x, 0.f));
    hv[5] = (short)f2bf(fmaxf(pb2.y + eb.y, 0.f));
    hv[6] = (short)f2bf(fmaxf(pb2.z + eb.z, 0.f));
    hv[7] = (short)f2bf(fmaxf(pb2.w + eb.w, 0.f));
    *(bf16x8*)(hrow + (size_t)u * JH_ + kcol) = hv;
  }
}

// ---------------------------------------------------------------------------
// Pure GEMM (m97-style): C[m][n] = hB[m][:] . Wout[n][:] + bout[n]
// 128x128 tile, 256 thr = 4 waves (2x2, 64x64 each), both operands via
// global_load_lds w=16, pre-swizzled source. 1D grid, XCD-bijective swizzle
// so the 8 n-tiles of one m-tile run on the same XCD (A-tile L2 reuse).
// ---------------------------------------------------------------------------
template<int BF16OUT>
__global__ void k_gemm_logits(const u16* __restrict__ A, const u16* __restrict__ Bm,
                              const float* __restrict__ bout, float* __restrict__ outF,
                              u16* __restrict__ outB) {
  __shared__ __align__(16) u16 sA[128 * 64];
  __shared__ __align__(16) u16 sB[128 * 64];
  // bijective XCD swizzle: 8192 blocks, 8 XCDs -> XCD x gets m-tiles [x*128,(x+1)*128)
  int wg = (blockIdx.x & 7) * 1024 + (blockIdx.x >> 3);
  int n0 = (wg & 7) * 128;          // n fastest: 8 consecutive blocks share A-tile
  int m0 = (wg >> 3) * 128;
  int tid = threadIdx.x, lane = tid & 63, wid = tid >> 6;

  f32x4 acc[4][4] = {};
  for (int kk = 0; kk < JH_; kk += 64) {
#pragma unroll
    for (int i = 0; i < 4; i++) {
      int cbase = wid * 256 + i * 64;
      int c = cbase + lane;
      int r = c >> 3;
      int kc = (c & 7) ^ (r & 7);
      gload16(A + (size_t)(m0 + r) * JH_ + kk + kc * 8, sA + (size_t)cbase * 8);
      gload16(Bm + (size_t)(n0 + r) * JH_ + kk + kc * 8, sB + (size_t)cbase * 8);
    }
    __syncthreads();
    int wr = (wid >> 1) * 64, wc = (wid & 1) * 64;
    int lr = lane & 15, lk = lane >> 4;
#pragma unroll
    for (int ki = 0; ki < 2; ki++) {
      bf16x8 af[4], bq[4];
#pragma unroll
      for (int mf = 0; mf < 4; mf++) {
        int r = wr + mf * 16 + lr;
        int kc = ki * 4 + lk;
        int s = (r << 3) | (kc ^ (r & 7));
        af[mf] = *(const bf16x8*)(sA + s * 8);
      }
#pragma unroll
      for (int nf = 0; nf < 4; nf++) {
        int r = wc + nf * 16 + lr;
        int kc = ki * 4 + lk;
        int s = (r << 3) | (kc ^ (r & 7));
        bq[nf] = *(const bf16x8*)(sB + s * 8);
      }
#pragma unroll
      for (int mf = 0; mf < 4; mf++)
#pragma unroll
        for (int nf = 0; nf < 4; nf++)
          acc[mf][nf] = __builtin_amdgcn_mfma_f32_16x16x32_bf16(af[mf], bq[nf], acc[mf][nf], 0, 0, 0);
    }
    __syncthreads();
  }
  int wr = (wid >> 1) * 64, wc = (wid & 1) * 64;
  int lr = lane & 15, lq = lane >> 4;
#pragma unroll
  for (int nf = 0; nf < 4; nf++) {
    int n = n0 + wc + nf * 16 + lr;
    float bv = bout[n];
#pragma unroll
    for (int mf = 0; mf < 4; mf++) {
#pragma unroll
      for (int r = 0; r < 4; r++) {
        int m = m0 + wr + mf * 16 + lq * 4 + r;
        float v = acc[mf][nf][r] + bv;
        if (BF16OUT) outB[(size_t)m * V_ + n] = f2bf(v);
        else         outF[(size_t)m * V_ + n] = v;
      }
    }
  }
}

// ---------------------------------------------------------------------------
// log_softmax from bf16 logits -> fp32 out. One block (256 thr) per row.
// ---------------------------------------------------------------------------
__global__ void k_logsoftmax_bf16(const u16* __restrict__ lg, float* __restrict__ out) {
  __shared__ float redm[4];
  __shared__ float reds[4];
  int row = blockIdx.x;
  int tid = threadIdx.x, lane = tid & 63, w = tid >> 6;
  const u16* pr = lg + (size_t)row * V_;
  ushort4 v4 = *(const ushort4*)(pr + tid * 4);
  float v0 = bf2f(v4.x), v1 = bf2f(v4.y), v2 = bf2f(v4.z), v3 = bf2f(v4.w);
  float mx = fmaxf(fmaxf(v0, v1), fmaxf(v2, v3));
#pragma unroll
  for (int o = 32; o > 0; o >>= 1) mx = fmaxf(mx, __shfl_xor(mx, o, 64));
  if (lane == 0) redm[w] = mx;
  __syncthreads();
  mx = fmaxf(fmaxf(redm[0], redm[1]), fmaxf(redm[2], redm[3]));
  float s = __expf(v0 - mx) + __expf(v1 - mx) + __expf(v2 - mx) + __expf(v3 - mx);
#pragma unroll
  for (int o = 32; o > 0; o >>= 1) s += __shfl_xor(s, o, 64);
  if (lane == 0) reds[w] = s;
  __syncthreads();
  s = reds[0] + reds[1] + reds[2] + reds[3];
  float lse = mx + __logf(s);
  float4 o4;
  o4.x = v0 - lse; o4.y = v1 - lse; o4.z = v2 - lse; o4.w = v3 - lse;
  *(float4*)(out + (size_t)row * V_ + tid * 4) = o4;
}

// ---------------------------------------------------------------------------
// Fallback (round-1) fused joint GEMM (fp32 logits to d_out)
// ---------------------------------------------------------------------------
__global__ void k_joint_gemm(const float* __restrict__ e, const float* __restrict__ p,
                             const u16* __restrict__ Wout, const float* __restrict__ bout,
                             float* __restrict__ out) {
  __shared__ __align__(16) u16 sH[128 * 64];
  __shared__ __align__(16) u16 sW[128 * 64];
  __shared__ __align__(16) float sE[JH_];
  int bidm = blockIdx.x;
  int n0 = blockIdx.y * 128;
  int b = bidm >> 8;
  const float* erow = e + (size_t)bidm * JH_;
  const float* pb = p + (size_t)b * U_ * JH_;
  int tid = threadIdx.x, lane = tid & 63, wid = tid >> 6;

  for (int i = tid; i < JH_; i += 256) sE[i] = erow[i];
  __syncthreads();

  f32x4 acc[4][4] = {};
  for (int kk = 0; kk < JH_; kk += 64) {
#pragma unroll
    for (int i = 0; i < 4; i++) {
      int cbase = wid * 256 + i * 64;
      int c = cbase + lane;
      int r = c >> 3;
      int kc = (c & 7) ^ (r & 7);
      gload16(Wout + (size_t)(n0 + r) * JH_ + kk + kc * 8, sW + (size_t)cbase * 8);
    }
#pragma unroll
    for (int i = 0; i < 4; i++) {
      int c = tid + i * 256;
      int u = c >> 3, kc = c & 7;
      int kcol = kk + kc * 8;
      const float* pp = pb + (size_t)u * JH_;
      float4 pa = *(const float4*)(pp + kcol);
      float4 pb2 = *(const float4*)(pp + kcol + 4);
      float4 ea = *(const float4*)(sE + kcol);
      float4 eb = *(const float4*)(sE + kcol + 4);
      bf16x8 hv;
      hv[0] = (short)f2bf(fmaxf(pa.x + ea.x, 0.f));
      hv[1] = (short)f2bf(fmaxf(pa.y + ea.y, 0.f));
      hv[2] = (short)f2bf(fmaxf(pa.z + ea.z, 0.f));
      hv[3] = (short)f2bf(fmaxf(pa.w + ea.w, 0.f));
      hv[4] = (short)f2bf(fmaxf(pb2.x + eb.x, 0.f));
      hv[5] = (short)f2bf(fmaxf(pb2.y + eb.y, 0.f));
      hv[6] = (short)f2bf(fmaxf(pb2.z + eb.z, 0.f));
      hv[7] = (short)f2bf(fmaxf(pb2.w + eb.w, 0.f));
      int s = (u << 3) | (kc ^ (u & 7));
      *(bf16x8*)(sH + s * 8) = hv;
    }
    __syncthreads();
    int wr = (wid >> 1) * 64, wc = (wid & 1) * 64;
    int lr = lane & 15, lk = lane >> 4;
#pragma unroll
    for (int ki = 0; ki < 2; ki++) {
      bf16x8 af[4], bq[4];
#pragma unroll
      for (int mf = 0; mf < 4; mf++) {
        int r = wr + mf * 16 + lr;
        int kc = ki * 4 + lk;
        int s = (r << 3) | (kc ^ (r & 7));
        af[mf] = *(const bf16x8*)(sH + s * 8);
      }
#pragma unroll
      for (int nf = 0; nf < 4; nf++) {
        int r = wc + nf * 16 + lr;
        int kc = ki * 4 + lk;
        int s = (r << 3) | (kc ^ (r & 7));
        bq[nf] = *(const bf16x8*)(sW + s * 8);
      }
#pragma unroll
      for (int mf = 0; mf < 4; mf++)
#pragma unroll
        for (int nf = 0; nf < 4; nf++)
          acc[mf][nf] = __builtin_amdgcn_mfma_f32_16x16x32_bf16(af[mf], bq[nf], acc[mf][nf], 0, 0, 0);
    }
    __syncthreads();
  }
  int wr = (wid >> 1) * 64, wc = (wid & 1) * 64;
  int lr = lane & 15, lq = lane >> 4;
  float* orow = out + (size_t)bidm * U_ * V_;
#pragma unroll
  for (int nf = 0; nf < 4; nf++) {
    int n = n0 + wc + nf * 16 + lr;
    float bv = bout[n];
#pragma unroll
    for (int mf = 0; mf < 4; mf++) {
#pragma unroll
      for (int r = 0; r < 4; r++) {
        int u = wr + mf * 16 + lq * 4 + r;
        orow[(size_t)u * V_ + n] = acc[mf][nf][r] + bv;
      }
    }
  }
}

// ---------------------------------------------------------------------------
// In-place fp32 log_softmax (fallback), one wave per row
// ---------------------------------------------------------------------------
__global__ void k_logsoftmax(float* __restrict__ out) {
  int row = blockIdx.x * 4 + (threadIdx.x >> 6);
  int lane = threadIdx.x & 63;
  float* pr = out + (size_t)row * V_;
  float4 v[4];
  float mx = -1e30f;
#pragma unroll
  for (int i = 0; i < 4; i++) {
    v[i] = *(const float4*)(pr + (lane + i * 64) * 4);
    mx = fmaxf(mx, fmaxf(fmaxf(v[i].x, v[i].y), fmaxf(v[i].z, v[i].w)));
  }
#pragma unroll
  for (int o = 32; o > 0; o >>= 1) mx = fmaxf(mx, __shfl_xor(mx, o, 64));
  float s = 0.f;
#pragma unroll
  for (int i = 0; i < 4; i++) {
    s += __expf(v[i].x - mx) + __expf(v[i].y - mx) +
         __expf(v[i].z - mx) + __expf(v[i].w - mx);
  }
#pragma unroll
  for (int o = 32; o > 0; o >>= 1) s += __shfl_xor(s, o, 64);
  float lse = mx + __logf(s);
#pragma unroll
  for (int i = 0; i < 4; i++) {
    float4 w;
    w.x = v[i].x - lse; w.y = v[i].y - lse; w.z = v[i].z - lse; w.w = v[i].w - lse;
    *(float4*)(pr + (lane + i * 64) * 4) = w;
  }
}

// ---------------------------------------------------------------------------
extern "C" void kernel_launch(void* const* d_in, const int* in_sizes, int n_in,
                              void* d_out, int out_size, void* d_ws, size_t ws_size,
                              hipStream_t stream) {
  const float* enc    = (const float*)d_in[0];
  const float* dec    = (const float*)d_in[1];
  const float* W_enc  = (const float*)d_in[2];
  const float* b_enc  = (const float*)d_in[3];
  const float* W_pred = (const float*)d_in[4];
  const float* b_pred = (const float*)d_in[5];
  const float* W_out  = (const float*)d_in[6];
  const float* b_out  = (const float*)d_in[7];
  float* out = (float*)d_out;

  char* ws = (char*)d_ws;
  size_t off = 0;
  auto alloc = [&](size_t bytes) {
    void* pp = ws + off;
    off = (off + bytes + 255) & ~(size_t)255;
    return pp;
  };
  u16* encT   = (u16*)alloc((size_t)B_ * T_ * EH_ * 2);
  u16* decT   = (u16*)alloc((size_t)B_ * U_ * PH_ * 2);
  u16* WencB  = (u16*)alloc((size_t)JH_ * EH_ * 2);
  u16* WpredB = (u16*)alloc((size_t)JH_ * PH_ * 2);
  u16* WoutB  = (u16*)alloc((size_t)V_ * JH_ * 2);
  float* eBuf = (float*)alloc((size_t)B_ * T_ * JH_ * 4);
  float* pBuf = (float*)alloc((size_t)B_ * U_ * JH_ * 4);

  const size_t M = (size_t)B_ * T_ * U_;           // 131072
  const size_t need_h = M * JH_ * 2;               // 167.8 MB
  const size_t need_l = M * V_ * 2;                // 268.4 MB
  bool haveH = (off + need_h + 256) <= ws_size;
  u16* hB = haveH ? (u16*)alloc(need_h) : nullptr;
  bool haveL = haveH && (off + need_l + 256) <= ws_size;
  u16* lgB = haveL ? (u16*)alloc(need_l) : nullptr;

  // common front-end
  k_transpose_cvt<<<dim3(T_ / 32, EH_ / 32, B_), 256, 0, stream>>>(enc, encT, EH_, T_);
  k_transpose_cvt<<<dim3(U_ / 32, PH_ / 32, B_), 256, 0, stream>>>(dec, decT, PH_, U_);
  k_cvt_bf16<<<(JH_ * EH_ / 4 + 255) / 256, 256, 0, stream>>>(W_enc, WencB, JH_ * EH_);
  k_cvt_bf16<<<(JH_ * PH_ / 4 + 255) / 256, 256, 0, stream>>>(W_pred, WpredB, JH_ * PH_);
  k_cvt_bf16<<<(V_ * JH_ / 4 + 255) / 256, 256, 0, stream>>>(W_out, WoutB, V_ * JH_);
  k_proj_gemm<<<dim3(T_ / 64, JH_ / 64, B_), 256, 0, stream>>>(
      encT, WencB, b_enc, eBuf, EH_, JH_, (size_t)T_ * EH_, (size_t)T_ * JH_);
  k_proj_gemm<<<dim3(U_ / 64, JH_ / 64, B_), 256, 0, stream>>>(
      decT, WpredB, b_pred, pBuf, PH_, JH_, (size_t)U_ * PH_, (size_t)U_ * JH_);

  if (haveH) {
    k_hbuild<<<B_ * T_, 256, 0, stream>>>(eBuf, pBuf, hB);
    int nblk = (int)(M / 128) * (V_ / 128);        // 8192
    if (haveL) {
      k_gemm_logits<1><<<nblk, 256, 0, stream>>>(hB, WoutB, b_out, nullptr, lgB);
      k_logsoftmax_bf16<<<(int)M, 256, 0, stream>>>(lgB, out);
    } else {
      k_gemm_logits<0><<<nblk, 256, 0, stream>>>(hB, WoutB, b_out, out, nullptr);
      k_logsoftmax<<<(int)(M / 4), 256, 0, stream>>>(out);
    }
  } else {
    k_joint_gemm<<<dim3(B_ * T_, V_ / 128), 256, 0, stream>>>(eBuf, pBuf, WoutB, b_out, out);
    k_logsoftmax<<<(int)(M / 4), 256, 0, stream>>>(out);
  }
}

// Round 3
// 456.843 us; speedup vs baseline: 1.2896x; 1.0018x over previous
//
#include <hip/hip_runtime.h>
#include <hip/hip_bf16.h>
#include <stdint.h>

#define B_ 4
#define T_ 256
#define U_ 128
#define EH_ 1024
#define PH_ 640
#define JH_ 640
#define V_ 1024

typedef short bf16x8 __attribute__((ext_vector_type(8)));
typedef float f32x4 __attribute__((ext_vector_type(4)));
typedef unsigned short u16;

typedef const __attribute__((address_space(1))) uint32_t cgu32_t;
typedef __attribute__((address_space(3))) uint32_t lu32_t;

__device__ __forceinline__ u16 f2bf(float f) {
  union { float f; uint32_t u; } v;
  v.f = f;
  uint32_t u = v.u;
  return (u16)((u + 0x7FFFu + ((u >> 16) & 1u)) >> 16);
}

__device__ __forceinline__ float bf2f(u16 x) {
  union { uint32_t u; float f; } v;
  v.u = (uint32_t)x << 16;
  return v.f;
}

__device__ __forceinline__ void gload16(const void* g, void* l) {
  __builtin_amdgcn_global_load_lds((cgu32_t*)g, (lu32_t*)l, 16, 0, 0);
}

// ---------------------------------------------------------------------------
// Transpose + fp32->bf16: in [batch][H][W] -> out [batch][W][H]
// ---------------------------------------------------------------------------
__global__ void k_transpose_cvt(const float* __restrict__ in, u16* __restrict__ out,
                                int H, int W) {
  __shared__ float tile[32][33];
  int b = blockIdx.z;
  int h0 = blockIdx.y * 32, w0 = blockIdx.x * 32;
  const float* pin = in + (size_t)b * H * W;
  u16* pout = out + (size_t)b * H * W;
  int lw = threadIdx.x & 31, lh = threadIdx.x >> 5;
#pragma unroll
  for (int i = 0; i < 4; i++) {
    int h = lh + i * 8;
    tile[h][lw] = pin[(size_t)(h0 + h) * W + (w0 + lw)];
  }
  __syncthreads();
#pragma unroll
  for (int i = 0; i < 4; i++) {
    int w = lh + i * 8;
    pout[(size_t)(w0 + w) * H + (h0 + lw)] = f2bf(tile[lw][w]);
  }
}

// ---------------------------------------------------------------------------
// Flat fp32 -> bf16 convert (n divisible by 4)
// ---------------------------------------------------------------------------
__global__ void k_cvt_bf16(const float* __restrict__ in, u16* __restrict__ out, int n) {
  int i = blockIdx.x * blockDim.x + threadIdx.x;
  int idx = i * 4;
  if (idx < n) {
    float4 v = *(const float4*)(in + idx);
    ushort4 o;
    o.x = f2bf(v.x); o.y = f2bf(v.y); o.z = f2bf(v.z); o.w = f2bf(v.w);
    *(ushort4*)(out + idx) = o;
  }
}

// ---------------------------------------------------------------------------
// Projection GEMM: C[m][n] = sum_k A[m][k]*Bm[n][k] + bias[n]
// ---------------------------------------------------------------------------
__global__ void k_proj_gemm(const u16* __restrict__ A, const u16* __restrict__ Bm,
                            const float* __restrict__ bias, float* __restrict__ C,
                            int K, int N, size_t strideA, size_t strideC) {
  __shared__ __align__(16) u16 sA[64 * 64];
  __shared__ __align__(16) u16 sB[64 * 64];
  int bb = blockIdx.z;
  const u16* Ab = A + (size_t)bb * strideA;
  float* Cb = C + (size_t)bb * strideC;
  int m0 = blockIdx.x * 64, n0 = blockIdx.y * 64;
  int tid = threadIdx.x;
  int lane = tid & 63, wid = tid >> 6;

  f32x4 acc[2][2] = {};
  for (int kk = 0; kk < K; kk += 64) {
#pragma unroll
    for (int i = 0; i < 2; i++) {
      int c = tid + i * 256;
      int r = c >> 3, kc = c & 7;
      int s = (r << 3) | (kc ^ (r & 7));
      *(bf16x8*)(sA + s * 8) = *(const bf16x8*)(Ab + (size_t)(m0 + r) * K + kk + kc * 8);
      *(bf16x8*)(sB + s * 8) = *(const bf16x8*)(Bm + (size_t)(n0 + r) * K + kk + kc * 8);
    }
    __syncthreads();
    int wr = (wid >> 1) * 32, wc = (wid & 1) * 32;
    int lr = lane & 15, lk = lane >> 4;
#pragma unroll
    for (int ki = 0; ki < 2; ki++) {
      bf16x8 af[2], bq[2];
#pragma unroll
      for (int mf = 0; mf < 2; mf++) {
        int r = wr + mf * 16 + lr;
        int kc = ki * 4 + lk;
        int s = (r << 3) | (kc ^ (r & 7));
        af[mf] = *(const bf16x8*)(sA + s * 8);
      }
#pragma unroll
      for (int nf = 0; nf < 2; nf++) {
        int r = wc + nf * 16 + lr;
        int kc = ki * 4 + lk;
        int s = (r << 3) | (kc ^ (r & 7));
        bq[nf] = *(const bf16x8*)(sB + s * 8);
      }
#pragma unroll
      for (int mf = 0; mf < 2; mf++)
#pragma unroll
        for (int nf = 0; nf < 2; nf++)
          acc[mf][nf] = __builtin_amdgcn_mfma_f32_16x16x32_bf16(af[mf], bq[nf], acc[mf][nf], 0, 0, 0);
    }
    __syncthreads();
  }
  int wr = (wid >> 1) * 32, wc = (wid & 1) * 32;
  int lr = lane & 15, lq = lane >> 4;
#pragma unroll
  for (int nf = 0; nf < 2; nf++) {
    int n = n0 + wc + nf * 16 + lr;
    float bv = bias[n];
#pragma unroll
    for (int mf = 0; mf < 2; mf++) {
#pragma unroll
      for (int r = 0; r < 4; r++) {
        int m = m0 + wr + mf * 16 + lq * 4 + r;
        Cb[(size_t)m * N + n] = acc[mf][nf][r] + bv;
      }
    }
  }
}

// ---------------------------------------------------------------------------
// H materialization: hB[((b*T+t)*U+u)][k] = bf16(relu(e[b,t,k] + p[b,u,k]))
// ---------------------------------------------------------------------------
__global__ void k_hbuild(const float* __restrict__ e, const float* __restrict__ p,
                         u16* __restrict__ hB) {
  __shared__ __align__(16) float sE[JH_];
  int bidm = blockIdx.x;            // b*T + t
  int b = bidm >> 8;
  const float* erow = e + (size_t)bidm * JH_;
  const float* pb = p + (size_t)b * U_ * JH_;
  u16* hrow = hB + (size_t)bidm * U_ * JH_;
  int tid = threadIdx.x;
  for (int i = tid; i < JH_; i += 256) sE[i] = erow[i];
  __syncthreads();
#pragma unroll
  for (int it = 0; it < 40; it++) {
    int g = it * 256 + tid;
    int u = g / 80;
    int kc = g - u * 80;
    int kcol = kc * 8;
    const float* pp = pb + (size_t)u * JH_ + kcol;
    float4 pa = *(const float4*)(pp);
    float4 pb2 = *(const float4*)(pp + 4);
    float4 ea = *(const float4*)(sE + kcol);
    float4 eb = *(const float4*)(sE + kcol + 4);
    bf16x8 hv;
    hv[0] = (short)f2bf(fmaxf(pa.x + ea.x, 0.f));
    hv[1] = (short)f2bf(fmaxf(pa.y + ea.y, 0.f));
    hv[2] = (short)f2bf(fmaxf(pa.z + ea.z, 0.f));
    hv[3] = (short)f2bf(fmaxf(pa.w + ea.w, 0.f));
    hv[4] = (short)f2bf(fmaxf(pb2.x + eb.x, 0.f));
    hv[5] = (short)f2bf(fmaxf(pb2.y + eb.y, 0.f));
    hv[6] = (short)f2bf(fmaxf(pb2.z + eb.z, 0.f));
    hv[7] = (short)f2bf(fmaxf(pb2.w + eb.w, 0.f));
    *(bf16x8*)(hrow + (size_t)u * JH_ + kcol) = hv;
  }
}

// ---------------------------------------------------------------------------
// Pipelined GEMM (counted-vmcnt, never-drain): logits = hB . Wout^T + bout
// 128x128 tile, BK=32, 256 thr = 4 waves (2x2, 64x64 each).
// Triple-buffered LDS (3 x 16KB): stage tile t+2 into buf[(t+2)%3] while
// computing tile t from buf[t%3]; s_waitcnt vmcnt(4) + raw s_barrier keeps
// one K-tile (4 loads/thread) in flight across every barrier.
// Race-freedom: buf[(t+2)%3] was last read in iter t-1, whose ds_reads
// retired before its barrier; stage issues after that barrier.
// Swizzle (BK=32, 4 groups of 8/row): g ^= (r>>1)&3 -> 2-way (free) on
// ds_read_b128 fragment reads.
// ---------------------------------------------------------------------------
__global__ __launch_bounds__(256)
void k_gemm_p3(const u16* __restrict__ A, const u16* __restrict__ Bm,
               const float* __restrict__ bout, u16* __restrict__ outB) {
  __shared__ __align__(16) u16 lds[3 * 4096 * 2];   // 48 KB: 3 bufs x (A 4096 + B 4096)
  u16* sA = lds;
  u16* sB = lds + 3 * 4096;

  const int KT = JH_ / 32;          // 20 K-tiles
  // XCD-bijective swizzle: 8192 blocks, n fastest so 8 n-blocks share A-tile
  int wg = (blockIdx.x & 7) * 1024 + (blockIdx.x >> 3);
  int n0 = (wg & 7) * 128;
  int m0 = (wg >> 3) * 128;
  int tid = threadIdx.x, lane = tid & 63, wid = tid >> 6;
  int wr = (wid >> 1) * 64, wc = (wid & 1) * 64;
  int lr = lane & 15, lk = lane >> 4;

  // per-thread staging geometry (2 A-loads + 2 B-loads per K-tile)
  int sa0 = (wid * 2 + 0) * 64 + lane;   // slot ids
  int sa1 = (wid * 2 + 1) * 64 + lane;
  int ra0 = sa0 >> 2, ga0 = (sa0 & 3) ^ ((ra0 >> 1) & 3);
  int ra1 = sa1 >> 2, ga1 = (sa1 & 3) ^ ((ra1 >> 1) & 3);
  const u16* gA0 = A + (size_t)(m0 + ra0) * JH_ + ga0 * 8;
  const u16* gA1 = A + (size_t)(m0 + ra1) * JH_ + ga1 * 8;
  const u16* gB0 = Bm + (size_t)(n0 + ra0) * JH_ + ga0 * 8;
  const u16* gB1 = Bm + (size_t)(n0 + ra1) * JH_ + ga1 * 8;
  int da0 = (wid * 2 + 0) * 512;         // u16 offset of wave chunk
  int da1 = (wid * 2 + 1) * 512;

  f32x4 acc[4][4] = {};

#define STAGE(t, c)                                                         \
  do {                                                                      \
    int kk = (t) * 32;                                                      \
    u16* dA = sA + (c) * 4096;                                              \
    u16* dB = sB + (c) * 4096;                                              \
    gload16(gA0 + kk, dA + da0);                                            \
    gload16(gA1 + kk, dA + da1);                                            \
    gload16(gB0 + kk, dB + da0);                                            \
    gload16(gB1 + kk, dB + da1);                                            \
  } while (0)

  STAGE(0, 0);
  STAGE(1, 1);
  asm volatile("s_waitcnt vmcnt(4)" ::: "memory");
  __builtin_amdgcn_s_barrier();
  asm volatile("" ::: "memory");

  int c = 0;
  for (int t = 0; t < KT; t++) {
    int cs = c + 2; if (cs >= 3) cs -= 3;
    if (t + 2 < KT) STAGE(t + 2, cs);
    const u16* bA = sA + c * 4096;
    const u16* bB = sB + c * 4096;
    bf16x8 af[4], bq[4];
#pragma unroll
    for (int mf = 0; mf < 4; mf++) {
      int r = wr + mf * 16 + lr;
      int s = r * 4 + (lk ^ ((r >> 1) & 3));
      af[mf] = *(const bf16x8*)(bA + s * 8);
    }
#pragma unroll
    for (int nf = 0; nf < 4; nf++) {
      int r = wc + nf * 16 + lr;
      int s = r * 4 + (lk ^ ((r >> 1) & 3));
      bq[nf] = *(const bf16x8*)(bB + s * 8);
    }
#pragma unroll
    for (int mf = 0; mf < 4; mf++)
#pragma unroll
      for (int nf = 0; nf < 4; nf++)
        acc[mf][nf] = __builtin_amdgcn_mfma_f32_16x16x32_bf16(af[mf], bq[nf], acc[mf][nf], 0, 0, 0);

    __builtin_amdgcn_sched_barrier(0);
    if (t + 2 < KT) {
      asm volatile("s_waitcnt vmcnt(4)" ::: "memory");   // tile t+1 landed; t+2 in flight
    } else if (t + 1 < KT) {
      asm volatile("s_waitcnt vmcnt(0)" ::: "memory");   // last tile landed
    }
    if (t + 1 < KT) {
      __builtin_amdgcn_s_barrier();
      asm volatile("" ::: "memory");
    }
    c = c + 1; if (c == 3) c = 0;
  }
#undef STAGE

  int lq = lane >> 4;
#pragma unroll
  for (int nf = 0; nf < 4; nf++) {
    int n = n0 + wc + nf * 16 + lr;
    float bv = bout[n];
#pragma unroll
    for (int mf = 0; mf < 4; mf++) {
#pragma unroll
      for (int r = 0; r < 4; r++) {
        int m = m0 + wr + mf * 16 + lq * 4 + r;
        outB[(size_t)m * V_ + n] = f2bf(acc[mf][nf][r] + bv);
      }
    }
  }
}

// ---------------------------------------------------------------------------
// Fallback GEMM (m97-style) writing fp32 logits directly (no-lgB path)
// ---------------------------------------------------------------------------
__global__ void k_gemm_logits_f32(const u16* __restrict__ A, const u16* __restrict__ Bm,
                                  const float* __restrict__ bout, float* __restrict__ outF) {
  __shared__ __align__(16) u16 sA[128 * 64];
  __shared__ __align__(16) u16 sB[128 * 64];
  int wg = (blockIdx.x & 7) * 1024 + (blockIdx.x >> 3);
  int n0 = (wg & 7) * 128;
  int m0 = (wg >> 3) * 128;
  int tid = threadIdx.x, lane = tid & 63, wid = tid >> 6;

  f32x4 acc[4][4] = {};
  for (int kk = 0; kk < JH_; kk += 64) {
#pragma unroll
    for (int i = 0; i < 4; i++) {
      int cbase = wid * 256 + i * 64;
      int cc = cbase + lane;
      int r = cc >> 3;
      int kc = (cc & 7) ^ (r & 7);
      gload16(A + (size_t)(m0 + r) * JH_ + kk + kc * 8, sA + (size_t)cbase * 8);
      gload16(Bm + (size_t)(n0 + r) * JH_ + kk + kc * 8, sB + (size_t)cbase * 8);
    }
    __syncthreads();
    int wr = (wid >> 1) * 64, wc = (wid & 1) * 64;
    int lr = lane & 15, lk = lane >> 4;
#pragma unroll
    for (int ki = 0; ki < 2; ki++) {
      bf16x8 af[4], bq[4];
#pragma unroll
      for (int mf = 0; mf < 4; mf++) {
        int r = wr + mf * 16 + lr;
        int kc = ki * 4 + lk;
        int s = (r << 3) | (kc ^ (r & 7));
        af[mf] = *(const bf16x8*)(sA + s * 8);
      }
#pragma unroll
      for (int nf = 0; nf < 4; nf++) {
        int r = wc + nf * 16 + lr;
        int kc = ki * 4 + lk;
        int s = (r << 3) | (kc ^ (r & 7));
        bq[nf] = *(const bf16x8*)(sB + s * 8);
      }
#pragma unroll
      for (int mf = 0; mf < 4; mf++)
#pragma unroll
        for (int nf = 0; nf < 4; nf++)
          acc[mf][nf] = __builtin_amdgcn_mfma_f32_16x16x32_bf16(af[mf], bq[nf], acc[mf][nf], 0, 0, 0);
    }
    __syncthreads();
  }
  int wr = (wid >> 1) * 64, wc = (wid & 1) * 64;
  int lr = lane & 15, lq = lane >> 4;
#pragma unroll
  for (int nf = 0; nf < 4; nf++) {
    int n = n0 + wc + nf * 16 + lr;
    float bv = bout[n];
#pragma unroll
    for (int mf = 0; mf < 4; mf++) {
#pragma unroll
      for (int r = 0; r < 4; r++) {
        int m = m0 + wr + mf * 16 + lq * 4 + r;
        outF[(size_t)m * V_ + n] = acc[mf][nf][r] + bv;
      }
    }
  }
}

// ---------------------------------------------------------------------------
// log_softmax bf16 logits -> fp32, one WAVE per row (no block barriers)
// lane handles elems lane*4 + j*256, j=0..3 (coalesced 8B loads / 16B stores)
// ---------------------------------------------------------------------------
__global__ void k_logsoftmax_w(const u16* __restrict__ lg, float* __restrict__ out) {
  int row = blockIdx.x * 4 + (threadIdx.x >> 6);
  int lane = threadIdx.x & 63;
  const u16* pr = lg + (size_t)row * V_;
  float v[16];
  float mx = -1e30f;
#pragma unroll
  for (int j = 0; j < 4; j++) {
    ushort4 q = *(const ushort4*)(pr + lane * 4 + j * 256);
    v[j * 4 + 0] = bf2f(q.x); v[j * 4 + 1] = bf2f(q.y);
    v[j * 4 + 2] = bf2f(q.z); v[j * 4 + 3] = bf2f(q.w);
    mx = fmaxf(mx, fmaxf(fmaxf(v[j*4], v[j*4+1]), fmaxf(v[j*4+2], v[j*4+3])));
  }
#pragma unroll
  for (int o = 32; o > 0; o >>= 1) mx = fmaxf(mx, __shfl_xor(mx, o, 64));
  float s = 0.f;
#pragma unroll
  for (int i = 0; i < 16; i++) s += __expf(v[i] - mx);
#pragma unroll
  for (int o = 32; o > 0; o >>= 1) s += __shfl_xor(s, o, 64);
  float lse = mx + __logf(s);
  float* po = out + (size_t)row * V_;
#pragma unroll
  for (int j = 0; j < 4; j++) {
    float4 w;
    w.x = v[j*4+0] - lse; w.y = v[j*4+1] - lse;
    w.z = v[j*4+2] - lse; w.w = v[j*4+3] - lse;
    *(float4*)(po + lane * 4 + j * 256) = w;
  }
}

// ---------------------------------------------------------------------------
// In-place fp32 log_softmax (fallback), one wave per row
// ---------------------------------------------------------------------------
__global__ void k_logsoftmax(float* __restrict__ out) {
  int row = blockIdx.x * 4 + (threadIdx.x >> 6);
  int lane = threadIdx.x & 63;
  float* pr = out + (size_t)row * V_;
  float4 v[4];
  float mx = -1e30f;
#pragma unroll
  for (int i = 0; i < 4; i++) {
    v[i] = *(const float4*)(pr + (lane + i * 64) * 4);
    mx = fmaxf(mx, fmaxf(fmaxf(v[i].x, v[i].y), fmaxf(v[i].z, v[i].w)));
  }
#pragma unroll
  for (int o = 32; o > 0; o >>= 1) mx = fmaxf(mx, __shfl_xor(mx, o, 64));
  float s = 0.f;
#pragma unroll
  for (int i = 0; i < 4; i++) {
    s += __expf(v[i].x - mx) + __expf(v[i].y - mx) +
         __expf(v[i].z - mx) + __expf(v[i].w - mx);
  }
#pragma unroll
  for (int o = 32; o > 0; o >>= 1) s += __shfl_xor(s, o, 64);
  float lse = mx + __logf(s);
#pragma unroll
  for (int i = 0; i < 4; i++) {
    float4 w;
    w.x = v[i].x - lse; w.y = v[i].y - lse; w.z = v[i].z - lse; w.w = v[i].w - lse;
    *(float4*)(pr + (lane + i * 64) * 4) = w;
  }
}

// ---------------------------------------------------------------------------
extern "C" void kernel_launch(void* const* d_in, const int* in_sizes, int n_in,
                              void* d_out, int out_size, void* d_ws, size_t ws_size,
                              hipStream_t stream) {
  const float* enc    = (const float*)d_in[0];
  const float* dec    = (const float*)d_in[1];
  const float* W_enc  = (const float*)d_in[2];
  const float* b_enc  = (const float*)d_in[3];
  const float* W_pred = (const float*)d_in[4];
  const float* b_pred = (const float*)d_in[5];
  const float* W_out  = (const float*)d_in[6];
  const float* b_out  = (const float*)d_in[7];
  float* out = (float*)d_out;

  char* ws = (char*)d_ws;
  size_t off = 0;
  auto alloc = [&](size_t bytes) {
    void* pp = ws + off;
    off = (off + bytes + 255) & ~(size_t)255;
    return pp;
  };
  u16* encT   = (u16*)alloc((size_t)B_ * T_ * EH_ * 2);
  u16* decT   = (u16*)alloc((size_t)B_ * U_ * PH_ * 2);
  u16* WencB  = (u16*)alloc((size_t)JH_ * EH_ * 2);
  u16* WpredB = (u16*)alloc((size_t)JH_ * PH_ * 2);
  u16* WoutB  = (u16*)alloc((size_t)V_ * JH_ * 2);
  float* eBuf = (float*)alloc((size_t)B_ * T_ * JH_ * 4);
  float* pBuf = (float*)alloc((size_t)B_ * U_ * JH_ * 4);

  const size_t M = (size_t)B_ * T_ * U_;           // 131072
  const size_t need_h = M * JH_ * 2;               // 167.8 MB
  const size_t need_l = M * V_ * 2;                // 268.4 MB
  bool haveH = (off + need_h + 256) <= ws_size;
  u16* hB = haveH ? (u16*)alloc(need_h) : nullptr;
  bool haveL = haveH && (off + need_l + 256) <= ws_size;
  u16* lgB = haveL ? (u16*)alloc(need_l) : nullptr;

  // common front-end
  k_transpose_cvt<<<dim3(T_ / 32, EH_ / 32, B_), 256, 0, stream>>>(enc, encT, EH_, T_);
  k_transpose_cvt<<<dim3(U_ / 32, PH_ / 32, B_), 256, 0, stream>>>(dec, decT, PH_, U_);
  k_cvt_bf16<<<(JH_ * EH_ / 4 + 255) / 256, 256, 0, stream>>>(W_enc, WencB, JH_ * EH_);
  k_cvt_bf16<<<(JH_ * PH_ / 4 + 255) / 256, 256, 0, stream>>>(W_pred, WpredB, JH_ * PH_);
  k_cvt_bf16<<<(V_ * JH_ / 4 + 255) / 256, 256, 0, stream>>>(W_out, WoutB, V_ * JH_);
  k_proj_gemm<<<dim3(T_ / 64, JH_ / 64, B_), 256, 0, stream>>>(
      encT, WencB, b_enc, eBuf, EH_, JH_, (size_t)T_ * EH_, (size_t)T_ * JH_);
  k_proj_gemm<<<dim3(U_ / 64, JH_ / 64, B_), 256, 0, stream>>>(
      decT, WpredB, b_pred, pBuf, PH_, JH_, (size_t)U_ * PH_, (size_t)U_ * JH_);

  if (haveH) {
    k_hbuild<<<B_ * T_, 256, 0, stream>>>(eBuf, pBuf, hB);
    int nblk = (int)(M / 128) * (V_ / 128);        // 8192
    if (haveL) {
      k_gemm_p3<<<nblk, 256, 0, stream>>>(hB, WoutB, b_out, lgB);
      k_logsoftmax_w<<<(int)(M / 4), 256, 0, stream>>>(lgB, out);
    } else {
      k_gemm_logits_f32<<<nblk, 256, 0, stream>>>(hB, WoutB, b_out, out);
      k_logsoftmax<<<(int)(M / 4), 256, 0, stream>>>(out);
    }
  } else {
    // no-workspace fallback: direct fp32 GEMM from eBuf/pBuf is not available
    // without hB; reuse f32 GEMM path via on-the-fly H is removed — this
    // branch should not occur (ws is >2GB); keep a safe (slow) path anyway.
    k_gemm_logits_f32<<<(int)(M / 128) * (V_ / 128), 256, 0, stream>>>(hB, WoutB, b_out, out);
    k_logsoftmax<<<(int)(M / 4), 256, 0, stream>>>(out);
  }
}

// Round 4
// 389.970 us; speedup vs baseline: 1.5107x; 1.1715x over previous
//
#include <hip/hip_runtime.h>
#include <hip/hip_bf16.h>
#include <stdint.h>

#define B_ 4
#define T_ 256
#define U_ 128
#define EH_ 1024
#define PH_ 640
#define JH_ 640
#define V_ 1024

typedef short bf16x8 __attribute__((ext_vector_type(8)));
typedef float f32x4 __attribute__((ext_vector_type(4)));
typedef unsigned short u16;

typedef const __attribute__((address_space(1))) uint32_t cgu32_t;
typedef __attribute__((address_space(3))) uint32_t lu32_t;

__device__ __forceinline__ u16 f2bf(float f) {
  union { float f; uint32_t u; } v;
  v.f = f;
  uint32_t u = v.u;
  return (u16)((u + 0x7FFFu + ((u >> 16) & 1u)) >> 16);
}

__device__ __forceinline__ float bf2f(u16 x) {
  union { uint32_t u; float f; } v;
  v.u = (uint32_t)x << 16;
  return v.f;
}

__device__ __forceinline__ void gload16(const void* g, void* l) {
  __builtin_amdgcn_global_load_lds((cgu32_t*)g, (lu32_t*)l, 16, 0, 0);
}

// ---------------------------------------------------------------------------
// Transpose + fp32->bf16: in [batch][H][W] -> out [batch][W][H]
// ---------------------------------------------------------------------------
__global__ void k_transpose_cvt(const float* __restrict__ in, u16* __restrict__ out,
                                int H, int W) {
  __shared__ float tile[32][33];
  int b = blockIdx.z;
  int h0 = blockIdx.y * 32, w0 = blockIdx.x * 32;
  const float* pin = in + (size_t)b * H * W;
  u16* pout = out + (size_t)b * H * W;
  int lw = threadIdx.x & 31, lh = threadIdx.x >> 5;
#pragma unroll
  for (int i = 0; i < 4; i++) {
    int h = lh + i * 8;
    tile[h][lw] = pin[(size_t)(h0 + h) * W + (w0 + lw)];
  }
  __syncthreads();
#pragma unroll
  for (int i = 0; i < 4; i++) {
    int w = lh + i * 8;
    pout[(size_t)(w0 + w) * H + (h0 + lw)] = f2bf(tile[lw][w]);
  }
}

// ---------------------------------------------------------------------------
// Flat fp32 -> bf16 convert (n divisible by 4)
// ---------------------------------------------------------------------------
__global__ void k_cvt_bf16(const float* __restrict__ in, u16* __restrict__ out, int n) {
  int i = blockIdx.x * blockDim.x + threadIdx.x;
  int idx = i * 4;
  if (idx < n) {
    float4 v = *(const float4*)(in + idx);
    ushort4 o;
    o.x = f2bf(v.x); o.y = f2bf(v.y); o.z = f2bf(v.z); o.w = f2bf(v.w);
    *(ushort4*)(out + idx) = o;
  }
}

// ---------------------------------------------------------------------------
// Projection GEMM: C[m][n] = sum_k A[m][k]*Bm[n][k] + bias[n]
// ---------------------------------------------------------------------------
__global__ void k_proj_gemm(const u16* __restrict__ A, const u16* __restrict__ Bm,
                            const float* __restrict__ bias, float* __restrict__ C,
                            int K, int N, size_t strideA, size_t strideC) {
  __shared__ __align__(16) u16 sA[64 * 64];
  __shared__ __align__(16) u16 sB[64 * 64];
  int bb = blockIdx.z;
  const u16* Ab = A + (size_t)bb * strideA;
  float* Cb = C + (size_t)bb * strideC;
  int m0 = blockIdx.x * 64, n0 = blockIdx.y * 64;
  int tid = threadIdx.x;
  int lane = tid & 63, wid = tid >> 6;

  f32x4 acc[2][2] = {};
  for (int kk = 0; kk < K; kk += 64) {
#pragma unroll
    for (int i = 0; i < 2; i++) {
      int c = tid + i * 256;
      int r = c >> 3, kc = c & 7;
      int s = (r << 3) | (kc ^ (r & 7));
      *(bf16x8*)(sA + s * 8) = *(const bf16x8*)(Ab + (size_t)(m0 + r) * K + kk + kc * 8);
      *(bf16x8*)(sB + s * 8) = *(const bf16x8*)(Bm + (size_t)(n0 + r) * K + kk + kc * 8);
    }
    __syncthreads();
    int wr = (wid >> 1) * 32, wc = (wid & 1) * 32;
    int lr = lane & 15, lk = lane >> 4;
#pragma unroll
    for (int ki = 0; ki < 2; ki++) {
      bf16x8 af[2], bq[2];
#pragma unroll
      for (int mf = 0; mf < 2; mf++) {
        int r = wr + mf * 16 + lr;
        int kc = ki * 4 + lk;
        int s = (r << 3) | (kc ^ (r & 7));
        af[mf] = *(const bf16x8*)(sA + s * 8);
      }
#pragma unroll
      for (int nf = 0; nf < 2; nf++) {
        int r = wc + nf * 16 + lr;
        int kc = ki * 4 + lk;
        int s = (r << 3) | (kc ^ (r & 7));
        bq[nf] = *(const bf16x8*)(sB + s * 8);
      }
#pragma unroll
      for (int mf = 0; mf < 2; mf++)
#pragma unroll
        for (int nf = 0; nf < 2; nf++)
          acc[mf][nf] = __builtin_amdgcn_mfma_f32_16x16x32_bf16(af[mf], bq[nf], acc[mf][nf], 0, 0, 0);
    }
    __syncthreads();
  }
  int wr = (wid >> 1) * 32, wc = (wid & 1) * 32;
  int lr = lane & 15, lq = lane >> 4;
#pragma unroll
  for (int nf = 0; nf < 2; nf++) {
    int n = n0 + wc + nf * 16 + lr;
    float bv = bias[n];
#pragma unroll
    for (int mf = 0; mf < 2; mf++) {
#pragma unroll
      for (int r = 0; r < 4; r++) {
        int m = m0 + wr + mf * 16 + lq * 4 + r;
        Cb[(size_t)m * N + n] = acc[mf][nf][r] + bv;
      }
    }
  }
}

// ---------------------------------------------------------------------------
// H materialization: hB[((b*T+t)*U+u)][k] = bf16(relu(e[b,t,k] + p[b,u,k]))
// ---------------------------------------------------------------------------
__global__ void k_hbuild(const float* __restrict__ e, const float* __restrict__ p,
                         u16* __restrict__ hB) {
  __shared__ __align__(16) float sE[JH_];
  int bidm = blockIdx.x;            // b*T + t
  int b = bidm >> 8;
  const float* erow = e + (size_t)bidm * JH_;
  const float* pb = p + (size_t)b * U_ * JH_;
  u16* hrow = hB + (size_t)bidm * U_ * JH_;
  int tid = threadIdx.x;
  for (int i = tid; i < JH_; i += 256) sE[i] = erow[i];
  __syncthreads();
#pragma unroll
  for (int it = 0; it < 40; it++) {
    int g = it * 256 + tid;
    int u = g / 80;
    int kc = g - u * 80;
    int kcol = kc * 8;
    const float* pp = pb + (size_t)u * JH_ + kcol;
    float4 pa = *(const float4*)(pp);
    float4 pb2 = *(const float4*)(pp + 4);
    float4 ea = *(const float4*)(sE + kcol);
    float4 eb = *(const float4*)(sE + kcol + 4);
    bf16x8 hv;
    hv[0] = (short)f2bf(fmaxf(pa.x + ea.x, 0.f));
    hv[1] = (short)f2bf(fmaxf(pa.y + ea.y, 0.f));
    hv[2] = (short)f2bf(fmaxf(pa.z + ea.z, 0.f));
    hv[3] = (short)f2bf(fmaxf(pa.w + ea.w, 0.f));
    hv[4] = (short)f2bf(fmaxf(pb2.x + eb.x, 0.f));
    hv[5] = (short)f2bf(fmaxf(pb2.y + eb.y, 0.f));
    hv[6] = (short)f2bf(fmaxf(pb2.z + eb.z, 0.f));
    hv[7] = (short)f2bf(fmaxf(pb2.w + eb.w, 0.f));
    *(bf16x8*)(hrow + (size_t)u * JH_ + kcol) = hv;
  }
}

// ---------------------------------------------------------------------------
// 256x256 8-phase GEMM (T2+T3+T4+T5): lgB = hB . Wout^T + bout  (bf16 out)
// 512 thr = 8 waves (wm=wid>>2, wn=wid&3), interleaved frag ownership:
//   rows wm*16 + mf*32 (mf 0..7), cols wn*16 + nf*64 (nf 0..3)
// Phase (a,b) = C-quadrant: A-half a, B-half b only.
// LDS 128KB: buf[2] x { A: half[2] 16KB, B: half[2] 16KB }.
// Staging: gload_lds w=16, linear dest, inverse-XOR-swizzled source.
// Issue order per tile t (prefetch t+1): A0@p0, B0@p1, B1@p2, A1@p3.
// Waits: p0 vmcnt(4) [forces A0,B0,B1(t)], p2 vmcnt(6) [forces A1(t)];
// never drains in steady state.
// ---------------------------------------------------------------------------
__global__ __launch_bounds__(512, 2)
void k_gemm8(const u16* __restrict__ A, const u16* __restrict__ Bm,
             const float* __restrict__ bout, u16* __restrict__ outB) {
  __shared__ __align__(16) u16 lds[65536];   // 128 KB

  const int KT = 10;                // 640 / 64
  // bijective XCD swizzle: 2048 blocks, n fastest -> 4 n-blocks share A-tile
  int wg = (blockIdx.x & 7) * 256 + (blockIdx.x >> 3);
  int n0 = (wg & 3) * 256;
  int m0 = (wg >> 2) * 256;
  int tid = threadIdx.x, lane = tid & 63, wid = tid >> 6;
  int wm = wid >> 2, wn = wid & 3;
  int lr = lane & 15, lk = lane >> 4, lq = lk;

  // ---- staging geometry: slot s = call*512 + wid*64 + lane
  //      rl = s>>3 = call*64 + wid*8 + (lane>>3); store-group = (lane&7)^(lane>>3)
  int rl0 = wid * 8 + (lane >> 3);
  int cOff = ((lane & 7) ^ (lane >> 3)) * 8;
  const u16* pA = A + (size_t)(m0 + rl0) * JH_ + cOff;
  const u16* pB = Bm + (size_t)(n0 + rl0) * JH_ + cOff;
  int dBase = wid * 512;            // u16; + call*4096 + isB*16384 + half*8192 + buf*32768

  // ---- ds_read swizzled offsets (u16 units); row stride 64 u16 = 128B
  int aRow = (wm * 16 + lr) * 64;
  int bRow = (wn * 16 + lr) * 64;
  int sw0 = ((0 * 4 + lk) ^ (lr & 7)) * 8;
  int sw1 = ((1 * 4 + lk) ^ (lr & 7)) * 8;

  f32x4 acc[8][4] = {};
  bf16x8 af[4][2], bq[4][2];

#define ISSUE(tn, isB, half, buf)                                            \
  do {                                                                       \
    const u16* s_ = ((isB) ? pB : pA) + (size_t)(half) * (128 * JH_) + (tn) * 64; \
    u16* d_ = lds + (buf) * 32768 + (isB) * 16384 + (half) * 8192 + dBase;   \
    gload16(s_, d_);                                                         \
    gload16(s_ + 64 * JH_, d_ + 4096);                                       \
  } while (0)

  // prologue: tile 0 into buf 0, consumption order
  ISSUE(0, 0, 0, 0);
  ISSUE(0, 1, 0, 0);
  ISSUE(0, 1, 1, 0);
  ISSUE(0, 0, 1, 0);

  for (int t = 0; t < KT; t++) {
    int c = t & 1;
    const u16* lb = lds + c * 32768;
    int cn = c ^ 1;
    // ================= phase 0: quadrant (a=0,b=0) =================
    if (t + 1 < KT) ISSUE(t + 1, 0, 0, cn);
    __builtin_amdgcn_sched_barrier(0);
    if (t + 1 < KT) asm volatile("s_waitcnt vmcnt(4)" ::: "memory");
    else            asm volatile("s_waitcnt vmcnt(2)" ::: "memory");
    __builtin_amdgcn_s_barrier();
    asm volatile("" ::: "memory");
#pragma unroll
    for (int mfq = 0; mfq < 4; mfq++) {
      af[mfq][0] = *(const bf16x8*)(lb + aRow + mfq * 2048 + sw0);
      af[mfq][1] = *(const bf16x8*)(lb + aRow + mfq * 2048 + sw1);
    }
#pragma unroll
    for (int nf = 0; nf < 4; nf++) {
      const u16* bb = lb + 16384 + (nf >> 1) * 8192 + (nf & 1) * 4096 + bRow;
      bq[nf][0] = *(const bf16x8*)(bb + sw0);
      bq[nf][1] = *(const bf16x8*)(bb + sw1);
    }
    __builtin_amdgcn_s_setprio(1);
#pragma unroll
    for (int mfq = 0; mfq < 4; mfq++)
#pragma unroll
      for (int nf = 0; nf < 2; nf++)
#pragma unroll
        for (int kst = 0; kst < 2; kst++)
          acc[mfq][nf] = __builtin_amdgcn_mfma_f32_16x16x32_bf16(af[mfq][kst], bq[nf][kst], acc[mfq][nf], 0, 0, 0);
    __builtin_amdgcn_s_setprio(0);
    // ================= phase 1: quadrant (0,1) =================
    if (t + 1 < KT) ISSUE(t + 1, 1, 0, cn);
    __builtin_amdgcn_sched_barrier(0);
    __builtin_amdgcn_s_barrier();
    asm volatile("" ::: "memory");
    __builtin_amdgcn_s_setprio(1);
#pragma unroll
    for (int mfq = 0; mfq < 4; mfq++)
#pragma unroll
      for (int nf = 2; nf < 4; nf++)
#pragma unroll
        for (int kst = 0; kst < 2; kst++)
          acc[mfq][nf] = __builtin_amdgcn_mfma_f32_16x16x32_bf16(af[mfq][kst], bq[nf][kst], acc[mfq][nf], 0, 0, 0);
    __builtin_amdgcn_s_setprio(0);
    // ================= phase 2: quadrant (1,0) =================
    if (t + 1 < KT) ISSUE(t + 1, 1, 1, cn);
    __builtin_amdgcn_sched_barrier(0);
    if (t + 1 < KT) asm volatile("s_waitcnt vmcnt(6)" ::: "memory");
    else            asm volatile("s_waitcnt vmcnt(0)" ::: "memory");
    __builtin_amdgcn_s_barrier();
    asm volatile("" ::: "memory");
#pragma unroll
    for (int mfq = 0; mfq < 4; mfq++) {
      af[mfq][0] = *(const bf16x8*)(lb + 8192 + aRow + mfq * 2048 + sw0);
      af[mfq][1] = *(const bf16x8*)(lb + 8192 + aRow + mfq * 2048 + sw1);
    }
    __builtin_amdgcn_s_setprio(1);
#pragma unroll
    for (int mfq = 0; mfq < 4; mfq++)
#pragma unroll
      for (int nf = 0; nf < 2; nf++)
#pragma unroll
        for (int kst = 0; kst < 2; kst++)
          acc[4 + mfq][nf] = __builtin_amdgcn_mfma_f32_16x16x32_bf16(af[mfq][kst], bq[nf][kst], acc[4 + mfq][nf], 0, 0, 0);
    __builtin_amdgcn_s_setprio(0);
    // ================= phase 3: quadrant (1,1) =================
    if (t + 1 < KT) ISSUE(t + 1, 0, 1, cn);
    __builtin_amdgcn_sched_barrier(0);
    __builtin_amdgcn_s_barrier();
    asm volatile("" ::: "memory");
    __builtin_amdgcn_s_setprio(1);
#pragma unroll
    for (int mfq = 0; mfq < 4; mfq++)
#pragma unroll
      for (int nf = 2; nf < 4; nf++)
#pragma unroll
        for (int kst = 0; kst < 2; kst++)
          acc[4 + mfq][nf] = __builtin_amdgcn_mfma_f32_16x16x32_bf16(af[mfq][kst], bq[nf][kst], acc[4 + mfq][nf], 0, 0, 0);
    __builtin_amdgcn_s_setprio(0);
  }
#undef ISSUE

  // ---- epilogue: bias + bf16 store
#pragma unroll
  for (int nf = 0; nf < 4; nf++) {
    int n = n0 + wn * 16 + nf * 64 + lr;
    float bv = bout[n];
#pragma unroll
    for (int mf = 0; mf < 8; mf++) {
      int m = m0 + wm * 16 + mf * 32 + lq * 4;
      u16* po = outB + (size_t)m * V_ + n;
#pragma unroll
      for (int r = 0; r < 4; r++)
        po[(size_t)r * V_] = f2bf(acc[mf][nf][r] + bv);
    }
  }
}

// ---------------------------------------------------------------------------
// Fallback GEMM (m97-style) writing fp32 logits directly (no-lgB path)
// ---------------------------------------------------------------------------
__global__ void k_gemm_logits_f32(const u16* __restrict__ A, const u16* __restrict__ Bm,
                                  const float* __restrict__ bout, float* __restrict__ outF) {
  __shared__ __align__(16) u16 sA[128 * 64];
  __shared__ __align__(16) u16 sB[128 * 64];
  int wg = (blockIdx.x & 7) * 1024 + (blockIdx.x >> 3);
  int n0 = (wg & 7) * 128;
  int m0 = (wg >> 3) * 128;
  int tid = threadIdx.x, lane = tid & 63, wid = tid >> 6;

  f32x4 acc[4][4] = {};
  for (int kk = 0; kk < JH_; kk += 64) {
#pragma unroll
    for (int i = 0; i < 4; i++) {
      int cbase = wid * 256 + i * 64;
      int cc = cbase + lane;
      int r = cc >> 3;
      int kc = (cc & 7) ^ (r & 7);
      gload16(A + (size_t)(m0 + r) * JH_ + kk + kc * 8, sA + (size_t)cbase * 8);
      gload16(Bm + (size_t)(n0 + r) * JH_ + kk + kc * 8, sB + (size_t)cbase * 8);
    }
    __syncthreads();
    int wr = (wid >> 1) * 64, wc = (wid & 1) * 64;
    int lr = lane & 15, lk = lane >> 4;
#pragma unroll
    for (int ki = 0; ki < 2; ki++) {
      bf16x8 af[4], bq[4];
#pragma unroll
      for (int mf = 0; mf < 4; mf++) {
        int r = wr + mf * 16 + lr;
        int kc = ki * 4 + lk;
        int s = (r << 3) | (kc ^ (r & 7));
        af[mf] = *(const bf16x8*)(sA + s * 8);
      }
#pragma unroll
      for (int nf = 0; nf < 4; nf++) {
        int r = wc + nf * 16 + lr;
        int kc = ki * 4 + lk;
        int s = (r << 3) | (kc ^ (r & 7));
        bq[nf] = *(const bf16x8*)(sB + s * 8);
      }
#pragma unroll
      for (int mf = 0; mf < 4; mf++)
#pragma unroll
        for (int nf = 0; nf < 4; nf++)
          acc[mf][nf] = __builtin_amdgcn_mfma_f32_16x16x32_bf16(af[mf], bq[nf], acc[mf][nf], 0, 0, 0);
    }
    __syncthreads();
  }
  int wr = (wid >> 1) * 64, wc = (wid & 1) * 64;
  int lr = lane & 15, lq = lane >> 4;
#pragma unroll
  for (int nf = 0; nf < 4; nf++) {
    int n = n0 + wc + nf * 16 + lr;
    float bv = bout[n];
#pragma unroll
    for (int mf = 0; mf < 4; mf++) {
#pragma unroll
      for (int r = 0; r < 4; r++) {
        int m = m0 + wr + mf * 16 + lq * 4 + r;
        outF[(size_t)m * V_ + n] = acc[mf][nf][r] + bv;
      }
    }
  }
}

// ---------------------------------------------------------------------------
// log_softmax bf16 logits -> fp32, one WAVE per row
// ---------------------------------------------------------------------------
__global__ void k_logsoftmax_w(const u16* __restrict__ lg, float* __restrict__ out) {
  int row = blockIdx.x * 4 + (threadIdx.x >> 6);
  int lane = threadIdx.x & 63;
  const u16* pr = lg + (size_t)row * V_;
  float v[16];
  float mx = -1e30f;
#pragma unroll
  for (int j = 0; j < 4; j++) {
    ushort4 q = *(const ushort4*)(pr + lane * 4 + j * 256);
    v[j * 4 + 0] = bf2f(q.x); v[j * 4 + 1] = bf2f(q.y);
    v[j * 4 + 2] = bf2f(q.z); v[j * 4 + 3] = bf2f(q.w);
    mx = fmaxf(mx, fmaxf(fmaxf(v[j*4], v[j*4+1]), fmaxf(v[j*4+2], v[j*4+3])));
  }
#pragma unroll
  for (int o = 32; o > 0; o >>= 1) mx = fmaxf(mx, __shfl_xor(mx, o, 64));
  float s = 0.f;
#pragma unroll
  for (int i = 0; i < 16; i++) s += __expf(v[i] - mx);
#pragma unroll
  for (int o = 32; o > 0; o >>= 1) s += __shfl_xor(s, o, 64);
  float lse = mx + __logf(s);
  float* po = out + (size_t)row * V_;
#pragma unroll
  for (int j = 0; j < 4; j++) {
    float4 w;
    w.x = v[j*4+0] - lse; w.y = v[j*4+1] - lse;
    w.z = v[j*4+2] - lse; w.w = v[j*4+3] - lse;
    *(float4*)(po + lane * 4 + j * 256) = w;
  }
}

// ---------------------------------------------------------------------------
// In-place fp32 log_softmax (fallback), one wave per row
// ---------------------------------------------------------------------------
__global__ void k_logsoftmax(float* __restrict__ out) {
  int row = blockIdx.x * 4 + (threadIdx.x >> 6);
  int lane = threadIdx.x & 63;
  float* pr = out + (size_t)row * V_;
  float4 v[4];
  float mx = -1e30f;
#pragma unroll
  for (int i = 0; i < 4; i++) {
    v[i] = *(const float4*)(pr + (lane + i * 64) * 4);
    mx = fmaxf(mx, fmaxf(fmaxf(v[i].x, v[i].y), fmaxf(v[i].z, v[i].w)));
  }
#pragma unroll
  for (int o = 32; o > 0; o >>= 1) mx = fmaxf(mx, __shfl_xor(mx, o, 64));
  float s = 0.f;
#pragma unroll
  for (int i = 0; i < 4; i++) {
    s += __expf(v[i].x - mx) + __expf(v[i].y - mx) +
         __expf(v[i].z - mx) + __expf(v[i].w - mx);
  }
#pragma unroll
  for (int o = 32; o > 0; o >>= 1) s += __shfl_xor(s, o, 64);
  float lse = mx + __logf(s);
#pragma unroll
  for (int i = 0; i < 4; i++) {
    float4 w;
    w.x = v[i].x - lse; w.y = v[i].y - lse; w.z = v[i].z - lse; w.w = v[i].w - lse;
    *(float4*)(pr + (lane + i * 64) * 4) = w;
  }
}

// ---------------------------------------------------------------------------
extern "C" void kernel_launch(void* const* d_in, const int* in_sizes, int n_in,
                              void* d_out, int out_size, void* d_ws, size_t ws_size,
                              hipStream_t stream) {
  const float* enc    = (const float*)d_in[0];
  const float* dec    = (const float*)d_in[1];
  const float* W_enc  = (const float*)d_in[2];
  const float* b_enc  = (const float*)d_in[3];
  const float* W_pred = (const float*)d_in[4];
  const float* b_pred = (const float*)d_in[5];
  const float* W_out  = (const float*)d_in[6];
  const float* b_out  = (const float*)d_in[7];
  float* out = (float*)d_out;

  char* ws = (char*)d_ws;
  size_t off = 0;
  auto alloc = [&](size_t bytes) {
    void* pp = ws + off;
    off = (off + bytes + 255) & ~(size_t)255;
    return pp;
  };
  u16* encT   = (u16*)alloc((size_t)B_ * T_ * EH_ * 2);
  u16* decT   = (u16*)alloc((size_t)B_ * U_ * PH_ * 2);
  u16* WencB  = (u16*)alloc((size_t)JH_ * EH_ * 2);
  u16* WpredB = (u16*)alloc((size_t)JH_ * PH_ * 2);
  u16* WoutB  = (u16*)alloc((size_t)V_ * JH_ * 2);
  float* eBuf = (float*)alloc((size_t)B_ * T_ * JH_ * 4);
  float* pBuf = (float*)alloc((size_t)B_ * U_ * JH_ * 4);

  const size_t M = (size_t)B_ * T_ * U_;           // 131072
  const size_t need_h = M * JH_ * 2;               // 167.8 MB
  const size_t need_l = M * V_ * 2;                // 268.4 MB
  bool haveH = (off + need_h + 256) <= ws_size;
  u16* hB = haveH ? (u16*)alloc(need_h) : nullptr;
  bool haveL = haveH && (off + need_l + 256) <= ws_size;
  u16* lgB = haveL ? (u16*)alloc(need_l) : nullptr;

  // common front-end
  k_transpose_cvt<<<dim3(T_ / 32, EH_ / 32, B_), 256, 0, stream>>>(enc, encT, EH_, T_);
  k_transpose_cvt<<<dim3(U_ / 32, PH_ / 32, B_), 256, 0, stream>>>(dec, decT, PH_, U_);
  k_cvt_bf16<<<(JH_ * EH_ / 4 + 255) / 256, 256, 0, stream>>>(W_enc, WencB, JH_ * EH_);
  k_cvt_bf16<<<(JH_ * PH_ / 4 + 255) / 256, 256, 0, stream>>>(W_pred, WpredB, JH_ * PH_);
  k_cvt_bf16<<<(V_ * JH_ / 4 + 255) / 256, 256, 0, stream>>>(W_out, WoutB, V_ * JH_);
  k_proj_gemm<<<dim3(T_ / 64, JH_ / 64, B_), 256, 0, stream>>>(
      encT, WencB, b_enc, eBuf, EH_, JH_, (size_t)T_ * EH_, (size_t)T_ * JH_);
  k_proj_gemm<<<dim3(U_ / 64, JH_ / 64, B_), 256, 0, stream>>>(
      decT, WpredB, b_pred, pBuf, PH_, JH_, (size_t)U_ * PH_, (size_t)U_ * JH_);

  if (haveH) {
    k_hbuild<<<B_ * T_, 256, 0, stream>>>(eBuf, pBuf, hB);
    if (haveL) {
      int nblk = (int)(M / 256) * (V_ / 256);      // 2048
      k_gemm8<<<nblk, 512, 0, stream>>>(hB, WoutB, b_out, lgB);
      k_logsoftmax_w<<<(int)(M / 4), 256, 0, stream>>>(lgB, out);
    } else {
      int nblk = (int)(M / 128) * (V_ / 128);      // 8192
      k_gemm_logits_f32<<<nblk, 256, 0, stream>>>(hB, WoutB, b_out, out);
      k_logsoftmax<<<(int)(M / 4), 256, 0, stream>>>(out);
    }
  } else {
    k_gemm_logits_f32<<<(int)(M / 128) * (V_ / 128), 256, 0, stream>>>(hB, WoutB, b_out, out);
    k_logsoftmax<<<(int)(M / 4), 256, 0, stream>>>(out);
  }
}

// Round 5
// 374.435 us; speedup vs baseline: 1.5734x; 1.0415x over previous
//
#include <hip/hip_runtime.h>
#include <hip/hip_bf16.h>
#include <stdint.h>

#define B_ 4
#define T_ 256
#define U_ 128
#define EH_ 1024
#define PH_ 640
#define JH_ 640
#define V_ 1024
#define KT_ 20   // JH / 32 K-tiles

typedef short bf16x8 __attribute__((ext_vector_type(8)));
typedef float f32x4 __attribute__((ext_vector_type(4)));
typedef unsigned short u16;

typedef const __attribute__((address_space(1))) uint32_t cgu32_t;
typedef __attribute__((address_space(3))) uint32_t lu32_t;

__device__ __forceinline__ u16 f2bf(float f) {
  union { float f; uint32_t u; } v;
  v.f = f;
  uint32_t u = v.u;
  return (u16)((u + 0x7FFFu + ((u >> 16) & 1u)) >> 16);
}

__device__ __forceinline__ void gload16(const void* g, void* l) {
  __builtin_amdgcn_global_load_lds((cgu32_t*)g, (lu32_t*)l, 16, 0, 0);
}

#define VMW(n) asm volatile("s_waitcnt vmcnt(" #n ")" ::: "memory")
#define LGKM0  asm volatile("s_waitcnt lgkmcnt(0)" ::: "memory")
#define SCHEDB __builtin_amdgcn_sched_barrier(0)

// ---------------------------------------------------------------------------
// Transpose + fp32->bf16: in [batch][H][W] -> out [batch][W][H]
// ---------------------------------------------------------------------------
__global__ void k_transpose_cvt(const float* __restrict__ in, u16* __restrict__ out,
                                int H, int W) {
  __shared__ float tile[32][33];
  int b = blockIdx.z;
  int h0 = blockIdx.y * 32, w0 = blockIdx.x * 32;
  const float* pin = in + (size_t)b * H * W;
  u16* pout = out + (size_t)b * H * W;
  int lw = threadIdx.x & 31, lh = threadIdx.x >> 5;
#pragma unroll
  for (int i = 0; i < 4; i++) {
    int h = lh + i * 8;
    tile[h][lw] = pin[(size_t)(h0 + h) * W + (w0 + lw)];
  }
  __syncthreads();
#pragma unroll
  for (int i = 0; i < 4; i++) {
    int w = lh + i * 8;
    pout[(size_t)(w0 + w) * H + (h0 + lw)] = f2bf(tile[lw][w]);
  }
}

// ---------------------------------------------------------------------------
// Flat fp32 -> bf16 convert (n divisible by 4)
// ---------------------------------------------------------------------------
__global__ void k_cvt_bf16(const float* __restrict__ in, u16* __restrict__ out, int n) {
  int i = blockIdx.x * blockDim.x + threadIdx.x;
  int idx = i * 4;
  if (idx < n) {
    float4 v = *(const float4*)(in + idx);
    ushort4 o;
    o.x = f2bf(v.x); o.y = f2bf(v.y); o.z = f2bf(v.z); o.w = f2bf(v.w);
    *(ushort4*)(out + idx) = o;
  }
}

// ---------------------------------------------------------------------------
// Pack W_out (fp32 [V][JH]) into per-K-tile LDS-image layout (bf16):
// Wpk u16-index = ((t*4 + g)*1024 + c)*8 + j  ==  W_out[c][t*32 + g*8 + j]
// so staging is a flat, perfectly-coalesced 64KB copy per K-tile.
// ---------------------------------------------------------------------------
__global__ void k_pack_w(const float* __restrict__ W, u16* __restrict__ Wpk) {
  int s = blockIdx.x * 256 + threadIdx.x;   // 81920 slots
  int c = s & 1023;
  int g = (s >> 10) & 3;
  int t = s >> 12;
  const float* src = W + (size_t)c * JH_ + t * 32 + g * 8;
  float4 a = *(const float4*)src;
  float4 b2 = *(const float4*)(src + 4);
  ushort4 lo, hi;
  lo.x = f2bf(a.x);  lo.y = f2bf(a.y);  lo.z = f2bf(a.z);  lo.w = f2bf(a.w);
  hi.x = f2bf(b2.x); hi.y = f2bf(b2.y); hi.z = f2bf(b2.z); hi.w = f2bf(b2.w);
  u16* d = Wpk + (size_t)s * 8;
  *(ushort4*)d = lo;
  *(ushort4*)(d + 4) = hi;
}

// ---------------------------------------------------------------------------
// Projection GEMM: C[m][n] = sum_k A[m][k]*Bm[n][k] + bias[n]
// ---------------------------------------------------------------------------
__global__ void k_proj_gemm(const u16* __restrict__ A, const u16* __restrict__ Bm,
                            const float* __restrict__ bias, float* __restrict__ C,
                            int K, int N, size_t strideA, size_t strideC) {
  __shared__ __align__(16) u16 sA[64 * 64];
  __shared__ __align__(16) u16 sB[64 * 64];
  int bb = blockIdx.z;
  const u16* Ab = A + (size_t)bb * strideA;
  float* Cb = C + (size_t)bb * strideC;
  int m0 = blockIdx.x * 64, n0 = blockIdx.y * 64;
  int tid = threadIdx.x;
  int lane = tid & 63, wid = tid >> 6;

  f32x4 acc[2][2] = {};
  for (int kk = 0; kk < K; kk += 64) {
#pragma unroll
    for (int i = 0; i < 2; i++) {
      int c = tid + i * 256;
      int r = c >> 3, kc = c & 7;
      int s = (r << 3) | (kc ^ (r & 7));
      *(bf16x8*)(sA + s * 8) = *(const bf16x8*)(Ab + (size_t)(m0 + r) * K + kk + kc * 8);
      *(bf16x8*)(sB + s * 8) = *(const bf16x8*)(Bm + (size_t)(n0 + r) * K + kk + kc * 8);
    }
    __syncthreads();
    int wr = (wid >> 1) * 32, wc = (wid & 1) * 32;
    int lr = lane & 15, lk = lane >> 4;
#pragma unroll
    for (int ki = 0; ki < 2; ki++) {
      bf16x8 af[2], bq[2];
#pragma unroll
      for (int mf = 0; mf < 2; mf++) {
        int r = wr + mf * 16 + lr;
        int kc = ki * 4 + lk;
        int s = (r << 3) | (kc ^ (r & 7));
        af[mf] = *(const bf16x8*)(sA + s * 8);
      }
#pragma unroll
      for (int nf = 0; nf < 2; nf++) {
        int r = wc + nf * 16 + lr;
        int kc = ki * 4 + lk;
        int s = (r << 3) | (kc ^ (r & 7));
        bq[nf] = *(const bf16x8*)(sB + s * 8);
      }
#pragma unroll
      for (int mf = 0; mf < 2; mf++)
#pragma unroll
        for (int nf = 0; nf < 2; nf++)
          acc[mf][nf] = __builtin_amdgcn_mfma_f32_16x16x32_bf16(af[mf], bq[nf], acc[mf][nf], 0, 0, 0);
    }
    __syncthreads();
  }
  int wr = (wid >> 1) * 32, wc = (wid & 1) * 32;
  int lr = lane & 15, lq = lane >> 4;
#pragma unroll
  for (int nf = 0; nf < 2; nf++) {
    int n = n0 + wc + nf * 16 + lr;
    float bv = bias[n];
#pragma unroll
    for (int mf = 0; mf < 2; mf++) {
#pragma unroll
      for (int r = 0; r < 4; r++) {
        int m = m0 + wr + mf * 16 + lq * 4 + r;
        Cb[(size_t)m * N + n] = acc[mf][nf][r] + bv;
      }
    }
  }
}

// ---------------------------------------------------------------------------
// Fused joint GEMM + bias + log_softmax:
//   out[m][v] = log_softmax_v( relu(e[bt,:]+p[b,u,:]) . W_out[v,:] + b_out[v] )
// Block: 64 M-rows (one (b,t), u-half) x full V=1024. 512 thr = 8 waves,
// wave wn owns cols [wn*128, wn*128+128), all 64 rows. BK=32, 20 K-tiles.
// A built on the fly in LDS (tri-buffered, p prefetched 2 tiles ahead);
// B via global_load_lds from pre-packed Wpk (double-buffered, 2 half-stages
// per tile). Counted vmcnt(9) steady state - loads never drain in main loop.
// LDS: B 2x64KB | A 3x4KB | sE 2.5KB | reduce 4KB = 146.5KB.
// ---------------------------------------------------------------------------
__global__ __launch_bounds__(512)
void k_fused(const float* __restrict__ e, const float* __restrict__ p,
             const u16* __restrict__ Wpk, const float* __restrict__ bout,
             float* __restrict__ out) {
  __shared__ __align__(16) u16 lds[75008];
  u16* sB = lds;                         // 2 x 32768 u16
  u16* sA = lds + 65536;                 // 3 x 2048 u16
  float* sE = (float*)(lds + 71680);     // 640 f32
  float* redm = (float*)(lds + 72960);   // 64 x 8
  float* reds = redm + 512;              // 64 x 8

  int bid = blockIdx.x;
  int btile = bid >> 1;          // b*T + t
  int half = bid & 1;
  int b = btile >> 8;
  int tid = threadIdx.x, lane = tid & 63, wn = tid >> 6;
  int lr = lane & 15, lk = lane >> 4;

  const float* eRow = e + (size_t)btile * JH_;
  const float* pRow = p + ((size_t)b * U_ + half * 64) * JH_;
  float* outB = out + ((size_t)btile * U_ + half * 64) * V_;

  // per-thread A-build mapping: row r_, k-quad kq_ (4 k's)
  int r_ = tid >> 3, kq_ = tid & 7;
  const float* pSrc = pRow + (size_t)r_ * JH_ + kq_ * 4;
  int aw = (kq_ >> 1) * 512 + r_ * 8 + (kq_ & 1) * 4;   // u16 offset in A-buf
  int cb0 = 2 * wn, cb1 = 2 * wn + 1;                   // col-blocks this wave stages

  f32x4 acc[4][8] = {};

  for (int i = tid; i < JH_; i += 512) sE[i] = eRow[i];

  auto stage = [&](int t, int cb, int cbuf) {
#pragma unroll
    for (int g = 0; g < 4; g++)
      gload16(Wpk + (size_t)t * 32768 + g * 8192 + cb * 512 + lane * 8,
              sB + cbuf * 32768 + g * 8192 + cb * 512);
  };

  // ---- prologue: L(0), p(0), p(1), R(0); build A(0)
  stage(0, cb0, 0);
  float4 p0  = *(const float4*)(pSrc);
  float4 pvA = *(const float4*)(pSrc + 32);
  float4 pvB;
  stage(0, cb1, 0);
  LGKM0; SCHEDB;
  __builtin_amdgcn_s_barrier();          // sE visible
  {
    float4 ev = *(const float4*)(sE + kq_ * 4);
    ushort4 hv;
    hv.x = f2bf(fmaxf(p0.x + ev.x, 0.f));
    hv.y = f2bf(fmaxf(p0.y + ev.y, 0.f));
    hv.z = f2bf(fmaxf(p0.z + ev.z, 0.f));
    hv.w = f2bf(fmaxf(p0.w + ev.w, 0.f));
    *(ushort4*)(sA + aw) = hv;
  }
  LGKM0; SCHEDB;

  auto body = [&](int t, float4& pc, float4& pn) {
    int c = t & 1;
    const u16* Ab = sA + (t % 3) * 2048;
    const u16* Bb = sB + c * 32768 + lk * 8192;
    // ---------------- phase A ----------------
    if (t + 1 < KT_) stage(t + 1, cb0, c ^ 1);
    if (t + 2 < KT_) pn = *(const float4*)(pSrc + (t + 2) * 32);
    SCHEDB;
    if (t < KT_ - 2) { VMW(9); } else if (t == KT_ - 2) { VMW(8); } else { VMW(4); }
    SCHEDB;
    __builtin_amdgcn_s_barrier();
    if (t + 1 < KT_) {   // build A(t+1) from p(t+1) regs + sE
      float4 ev = *(const float4*)(sE + (t + 1) * 32 + kq_ * 4);
      ushort4 hv;
      hv.x = f2bf(fmaxf(pc.x + ev.x, 0.f));
      hv.y = f2bf(fmaxf(pc.y + ev.y, 0.f));
      hv.z = f2bf(fmaxf(pc.z + ev.z, 0.f));
      hv.w = f2bf(fmaxf(pc.w + ev.w, 0.f));
      *(ushort4*)(sA + ((t + 1) % 3) * 2048 + aw) = hv;
    }
    bf16x8 af[4], bq[4];
#pragma unroll
    for (int mf = 0; mf < 4; mf++)
      af[mf] = *(const bf16x8*)(Ab + lk * 512 + (mf * 16 + lr) * 8);
#pragma unroll
    for (int nf = 0; nf < 4; nf++)
      bq[nf] = *(const bf16x8*)(Bb + (wn * 128 + nf * 16 + lr) * 8);
    LGKM0; SCHEDB;
    __builtin_amdgcn_s_setprio(1);
#pragma unroll
    for (int mf = 0; mf < 4; mf++)
#pragma unroll
      for (int nf = 0; nf < 4; nf++)
        acc[mf][nf] = __builtin_amdgcn_mfma_f32_16x16x32_bf16(af[mf], bq[nf], acc[mf][nf], 0, 0, 0);
    __builtin_amdgcn_s_setprio(0);
    // ---------------- phase B ----------------
    if (t + 1 < KT_) stage(t + 1, cb1, c ^ 1);
    SCHEDB;
    if (t < KT_ - 2) { VMW(9); } else if (t == KT_ - 2) { VMW(8); } else { VMW(0); }
    SCHEDB;
    __builtin_amdgcn_s_barrier();
    bf16x8 bq2[4];
#pragma unroll
    for (int nf = 0; nf < 4; nf++)
      bq2[nf] = *(const bf16x8*)(Bb + (wn * 128 + (nf + 4) * 16 + lr) * 8);
    LGKM0; SCHEDB;
    __builtin_amdgcn_s_setprio(1);
#pragma unroll
    for (int mf = 0; mf < 4; mf++)
#pragma unroll
      for (int nf = 0; nf < 4; nf++)
        acc[mf][nf + 4] = __builtin_amdgcn_mfma_f32_16x16x32_bf16(af[mf], bq2[nf], acc[mf][nf + 4], 0, 0, 0);
    __builtin_amdgcn_s_setprio(0);
  };

  for (int t2 = 0; t2 < KT_; t2 += 2) {
    body(t2, pvA, pvB);
    body(t2 + 1, pvB, pvA);
  }

  // ---------------- epilogue: bias + log_softmax + fp32 store ----------------
  float bv[8];
#pragma unroll
  for (int nf = 0; nf < 8; nf++) bv[nf] = bout[wn * 128 + nf * 16 + lr];
#pragma unroll
  for (int mf = 0; mf < 4; mf++)
#pragma unroll
    for (int nf = 0; nf < 8; nf++)
#pragma unroll
      for (int r = 0; r < 4; r++)
        acc[mf][nf][r] += bv[nf];

  float gm[4][4];
#pragma unroll
  for (int mf = 0; mf < 4; mf++)
#pragma unroll
    for (int r = 0; r < 4; r++) {
      float m = acc[mf][0][r];
#pragma unroll
      for (int nf = 1; nf < 8; nf++) m = fmaxf(m, acc[mf][nf][r]);
#pragma unroll
      for (int o = 1; o < 16; o <<= 1) m = fmaxf(m, __shfl_xor(m, o, 64));
      gm[mf][r] = m;
    }
  if ((lane & 15) == 0) {
#pragma unroll
    for (int mf = 0; mf < 4; mf++)
#pragma unroll
      for (int r = 0; r < 4; r++)
        redm[(mf * 16 + lk * 4 + r) * 8 + wn] = gm[mf][r];
  }
  __syncthreads();
#pragma unroll
  for (int mf = 0; mf < 4; mf++)
#pragma unroll
    for (int r = 0; r < 4; r++) {
      int row = mf * 16 + lk * 4 + r;
      float m = redm[row * 8];
#pragma unroll
      for (int w = 1; w < 8; w++) m = fmaxf(m, redm[row * 8 + w]);
      gm[mf][r] = m;
    }
  float ls[4][4];
#pragma unroll
  for (int mf = 0; mf < 4; mf++)
#pragma unroll
    for (int r = 0; r < 4; r++) {
      float s = 0.f;
#pragma unroll
      for (int nf = 0; nf < 8; nf++) s += __expf(acc[mf][nf][r] - gm[mf][r]);
#pragma unroll
      for (int o = 1; o < 16; o <<= 1) s += __shfl_xor(s, o, 64);
      ls[mf][r] = s;
    }
  if ((lane & 15) == 0) {
#pragma unroll
    for (int mf = 0; mf < 4; mf++)
#pragma unroll
      for (int r = 0; r < 4; r++)
        reds[(mf * 16 + lk * 4 + r) * 8 + wn] = ls[mf][r];
  }
  __syncthreads();
#pragma unroll
  for (int mf = 0; mf < 4; mf++)
#pragma unroll
    for (int r = 0; r < 4; r++) {
      int row = mf * 16 + lk * 4 + r;
      float s = reds[row * 8];
#pragma unroll
      for (int w = 1; w < 8; w++) s += reds[row * 8 + w];
      ls[mf][r] = gm[mf][r] + __logf(s);
    }
#pragma unroll
  for (int mf = 0; mf < 4; mf++)
#pragma unroll
    for (int nf = 0; nf < 8; nf++)
#pragma unroll
      for (int r = 0; r < 4; r++)
        outB[(size_t)(mf * 16 + lk * 4 + r) * V_ + wn * 128 + nf * 16 + lr] =
            acc[mf][nf][r] - ls[mf][r];
}

// ---------------------------------------------------------------------------
extern "C" void kernel_launch(void* const* d_in, const int* in_sizes, int n_in,
                              void* d_out, int out_size, void* d_ws, size_t ws_size,
                              hipStream_t stream) {
  const float* enc    = (const float*)d_in[0];
  const float* dec    = (const float*)d_in[1];
  const float* W_enc  = (const float*)d_in[2];
  const float* b_enc  = (const float*)d_in[3];
  const float* W_pred = (const float*)d_in[4];
  const float* b_pred = (const float*)d_in[5];
  const float* W_out  = (const float*)d_in[6];
  const float* b_out  = (const float*)d_in[7];
  float* out = (float*)d_out;

  char* ws = (char*)d_ws;
  size_t off = 0;
  auto alloc = [&](size_t bytes) {
    void* pp = ws + off;
    off = (off + bytes + 255) & ~(size_t)255;
    return pp;
  };
  u16* encT   = (u16*)alloc((size_t)B_ * T_ * EH_ * 2);
  u16* decT   = (u16*)alloc((size_t)B_ * U_ * PH_ * 2);
  u16* WencB  = (u16*)alloc((size_t)JH_ * EH_ * 2);
  u16* WpredB = (u16*)alloc((size_t)JH_ * PH_ * 2);
  u16* Wpk    = (u16*)alloc((size_t)KT_ * 32768 * 2);
  float* eBuf = (float*)alloc((size_t)B_ * T_ * JH_ * 4);
  float* pBuf = (float*)alloc((size_t)B_ * U_ * JH_ * 4);

  // front-end
  k_transpose_cvt<<<dim3(T_ / 32, EH_ / 32, B_), 256, 0, stream>>>(enc, encT, EH_, T_);
  k_transpose_cvt<<<dim3(U_ / 32, PH_ / 32, B_), 256, 0, stream>>>(dec, decT, PH_, U_);
  k_cvt_bf16<<<(JH_ * EH_ / 4 + 255) / 256, 256, 0, stream>>>(W_enc, WencB, JH_ * EH_);
  k_cvt_bf16<<<(JH_ * PH_ / 4 + 255) / 256, 256, 0, stream>>>(W_pred, WpredB, JH_ * PH_);
  k_pack_w<<<(KT_ * 4096) / 256, 256, 0, stream>>>(W_out, Wpk);
  k_proj_gemm<<<dim3(T_ / 64, JH_ / 64, B_), 256, 0, stream>>>(
      encT, WencB, b_enc, eBuf, EH_, JH_, (size_t)T_ * EH_, (size_t)T_ * JH_);
  k_proj_gemm<<<dim3(U_ / 64, JH_ / 64, B_), 256, 0, stream>>>(
      decT, WpredB, b_pred, pBuf, PH_, JH_, (size_t)U_ * PH_, (size_t)U_ * JH_);

  // fused joint GEMM + log_softmax: one block per 64 output rows
  k_fused<<<B_ * T_ * 2, 512, 0, stream>>>(eBuf, pBuf, Wpk, b_out, out);
}

// Round 6
// 329.634 us; speedup vs baseline: 1.7872x; 1.1359x over previous
//
#include <hip/hip_runtime.h>
#include <hip/hip_bf16.h>
#include <stdint.h>

#define B_ 4
#define T_ 256
#define U_ 128
#define EH_ 1024
#define PH_ 640
#define JH_ 640
#define V_ 1024
#define KT_ 20   // JH / 32 K-tiles

typedef short bf16x8 __attribute__((ext_vector_type(8)));
typedef float f32x4 __attribute__((ext_vector_type(4)));
typedef unsigned short u16;

typedef const __attribute__((address_space(1))) uint32_t cgu32_t;
typedef __attribute__((address_space(3))) uint32_t lu32_t;

__device__ __forceinline__ u16 f2bf(float f) {
  union { float f; uint32_t u; } v;
  v.f = f;
  uint32_t u = v.u;
  return (u16)((u + 0x7FFFu + ((u >> 16) & 1u)) >> 16);
}

__device__ __forceinline__ void gload16(const void* g, void* l) {
  __builtin_amdgcn_global_load_lds((cgu32_t*)g, (lu32_t*)l, 16, 0, 0);
}

#define VMW(n) asm volatile("s_waitcnt vmcnt(" #n ")" ::: "memory")
#define LGKM0  asm volatile("s_waitcnt lgkmcnt(0)" ::: "memory")
#define SCHEDB __builtin_amdgcn_sched_barrier(0)

// ---------------------------------------------------------------------------
// Transpose + fp32->bf16: in [batch][H][W] -> out [batch][W][H]
// ---------------------------------------------------------------------------
__global__ void k_transpose_cvt(const float* __restrict__ in, u16* __restrict__ out,
                                int H, int W) {
  __shared__ float tile[32][33];
  int b = blockIdx.z;
  int h0 = blockIdx.y * 32, w0 = blockIdx.x * 32;
  const float* pin = in + (size_t)b * H * W;
  u16* pout = out + (size_t)b * H * W;
  int lw = threadIdx.x & 31, lh = threadIdx.x >> 5;
#pragma unroll
  for (int i = 0; i < 4; i++) {
    int h = lh + i * 8;
    tile[h][lw] = pin[(size_t)(h0 + h) * W + (w0 + lw)];
  }
  __syncthreads();
#pragma unroll
  for (int i = 0; i < 4; i++) {
    int w = lh + i * 8;
    pout[(size_t)(w0 + w) * H + (h0 + lw)] = f2bf(tile[lw][w]);
  }
}

// ---------------------------------------------------------------------------
// Merged weight prep: cvt W_enc, cvt W_pred, pack W_out (one launch)
// Wpk u16-index = ((t*4 + g)*1024 + c)*8 + j  ==  W_out[c][t*32 + g*8 + j]
// ---------------------------------------------------------------------------
__global__ void k_prep_w(const float* __restrict__ We, const float* __restrict__ Wp,
                         const float* __restrict__ Wo,
                         u16* __restrict__ WeB, u16* __restrict__ WpB,
                         u16* __restrict__ Wpk) {
  int s = blockIdx.x * 256 + threadIdx.x;
  if (s < 163840) {                       // W_enc: 655360 elems / 4
    int idx = s * 4;
    float4 v = *(const float4*)(We + idx);
    ushort4 o;
    o.x = f2bf(v.x); o.y = f2bf(v.y); o.z = f2bf(v.z); o.w = f2bf(v.w);
    *(ushort4*)(WeB + idx) = o;
  } else if (s < 266240) {                // W_pred: 409600 / 4
    int idx = (s - 163840) * 4;
    float4 v = *(const float4*)(Wp + idx);
    ushort4 o;
    o.x = f2bf(v.x); o.y = f2bf(v.y); o.z = f2bf(v.z); o.w = f2bf(v.w);
    *(ushort4*)(WpB + idx) = o;
  } else {                                // pack W_out: 81920 slots
    int q = s - 266240;
    int c = q & 1023;
    int g = (q >> 10) & 3;
    int t = q >> 12;
    const float* src = Wo + (size_t)c * JH_ + t * 32 + g * 8;
    float4 a = *(const float4*)src;
    float4 b2 = *(const float4*)(src + 4);
    ushort4 lo, hi;
    lo.x = f2bf(a.x);  lo.y = f2bf(a.y);  lo.z = f2bf(a.z);  lo.w = f2bf(a.w);
    hi.x = f2bf(b2.x); hi.y = f2bf(b2.y); hi.z = f2bf(b2.z); hi.w = f2bf(b2.w);
    u16* d = Wpk + (size_t)q * 8;
    *(ushort4*)d = lo;
    *(ushort4*)(d + 4) = hi;
  }
}

// ---------------------------------------------------------------------------
// Projection GEMM: C[m][n] = sum_k A[m][k]*Bm[n][k] + bias[n]
// ---------------------------------------------------------------------------
__global__ void k_proj_gemm(const u16* __restrict__ A, const u16* __restrict__ Bm,
                            const float* __restrict__ bias, float* __restrict__ C,
                            int K, int N, size_t strideA, size_t strideC) {
  __shared__ __align__(16) u16 sA[64 * 64];
  __shared__ __align__(16) u16 sB[64 * 64];
  int bb = blockIdx.z;
  const u16* Ab = A + (size_t)bb * strideA;
  float* Cb = C + (size_t)bb * strideC;
  int m0 = blockIdx.x * 64, n0 = blockIdx.y * 64;
  int tid = threadIdx.x;
  int lane = tid & 63, wid = tid >> 6;

  f32x4 acc[2][2] = {};
  for (int kk = 0; kk < K; kk += 64) {
#pragma unroll
    for (int i = 0; i < 2; i++) {
      int c = tid + i * 256;
      int r = c >> 3, kc = c & 7;
      int s = (r << 3) | (kc ^ (r & 7));
      *(bf16x8*)(sA + s * 8) = *(const bf16x8*)(Ab + (size_t)(m0 + r) * K + kk + kc * 8);
      *(bf16x8*)(sB + s * 8) = *(const bf16x8*)(Bm + (size_t)(n0 + r) * K + kk + kc * 8);
    }
    __syncthreads();
    int wr = (wid >> 1) * 32, wc = (wid & 1) * 32;
    int lr = lane & 15, lk = lane >> 4;
#pragma unroll
    for (int ki = 0; ki < 2; ki++) {
      bf16x8 af[2], bq[2];
#pragma unroll
      for (int mf = 0; mf < 2; mf++) {
        int r = wr + mf * 16 + lr;
        int kc = ki * 4 + lk;
        int s = (r << 3) | (kc ^ (r & 7));
        af[mf] = *(const bf16x8*)(sA + s * 8);
      }
#pragma unroll
      for (int nf = 0; nf < 2; nf++) {
        int r = wc + nf * 16 + lr;
        int kc = ki * 4 + lk;
        int s = (r << 3) | (kc ^ (r & 7));
        bq[nf] = *(const bf16x8*)(sB + s * 8);
      }
#pragma unroll
      for (int mf = 0; mf < 2; mf++)
#pragma unroll
        for (int nf = 0; nf < 2; nf++)
          acc[mf][nf] = __builtin_amdgcn_mfma_f32_16x16x32_bf16(af[mf], bq[nf], acc[mf][nf], 0, 0, 0);
    }
    __syncthreads();
  }
  int wr = (wid >> 1) * 32, wc = (wid & 1) * 32;
  int lr = lane & 15, lq = lane >> 4;
#pragma unroll
  for (int nf = 0; nf < 2; nf++) {
    int n = n0 + wc + nf * 16 + lr;
    float bv = bias[n];
#pragma unroll
    for (int mf = 0; mf < 2; mf++) {
#pragma unroll
      for (int r = 0; r < 4; r++) {
        int m = m0 + wr + mf * 16 + lq * 4 + r;
        Cb[(size_t)m * N + n] = acc[mf][nf][r] + bv;
      }
    }
  }
}

// ---------------------------------------------------------------------------
// Fused joint GEMM + bias + log_softmax (merged single-phase pipeline):
//   out[m][v] = log_softmax_v( relu(e[bt,:]+p[b,u,:]) . W_out[v,:] + b_out[v] )
// Block: 64 M-rows x full V=1024. 512 thr = 8 waves; wave wn owns cols
// [wn*128, wn*128+128) and self-stages exactly those columns (per-wave vmcnt
// ledger is sound; no cross-wave sB hazards). One barrier + one counted
// vmcnt per K-tile (32 MFMA). A built in LDS (4-slot ring, >=2-barrier WAR
// slack); p prefetched 2 tiles ahead into named regs. Steady vmcnt(9):
// outstanding = stage(t):8 + p(t+1):1 + stage(t+1):8 + p(t+2):1 = 18,
// forces oldest 9 = stage(t)+p(t+1). Tails: VMW(8) at KT-2, VMW(0) last.
// ---------------------------------------------------------------------------
__global__ __launch_bounds__(512)
void k_fused(const float* __restrict__ e, const float* __restrict__ p,
             const u16* __restrict__ Wpk, const float* __restrict__ bout,
             float* __restrict__ out) {
  __shared__ __align__(16) u16 sB[2][32768];   // [buf][g<4 | col<1024 | 8]
  __shared__ __align__(16) u16 sA[4][2048];    // [slot][lk<4 | row<64 | 8]
  __shared__ __align__(16) float sE[JH_];
  __shared__ float redm[512];
  __shared__ float reds[512];

  int bid = blockIdx.x;
  int btile = bid >> 1, half = bid & 1, b = btile >> 8;
  int tid = threadIdx.x, lane = tid & 63, wn = tid >> 6;
  int lr = lane & 15, lk = lane >> 4;

  const float* eRow = e + (size_t)btile * JH_;
  const float* pRow = p + ((size_t)b * U_ + half * 64) * JH_;
  float* outB = out + ((size_t)btile * U_ + half * 64) * V_;

  // A-build mapping: thread -> (row r_, k-quad kq_)
  int r_ = tid >> 3, kq_ = tid & 7;
  const float* pSrc = pRow + (size_t)r_ * JH_ + kq_ * 4;
  int aw = (kq_ >> 1) * 512 + r_ * 8 + (kq_ & 1) * 4;

  f32x4 acc[4][8] = {};

  auto stage = [&](int t, int c) {
    const u16* s0 = Wpk + (size_t)t * 32768 + (2 * wn) * 512 + lane * 8;
    u16* d0 = &sB[c][(2 * wn) * 512];
#pragma unroll
    for (int g = 0; g < 4; g++) {
      gload16(s0 + g * 8192, d0 + g * 8192);
      gload16(s0 + g * 8192 + 512, d0 + g * 8192 + 512);
    }
  };
  auto build = [&](int t, float4 pv) {
    float4 ev = *(const float4*)(&sE[t * 32 + kq_ * 4]);
    ushort4 hv;
    hv.x = f2bf(fmaxf(pv.x + ev.x, 0.f));
    hv.y = f2bf(fmaxf(pv.y + ev.y, 0.f));
    hv.z = f2bf(fmaxf(pv.z + ev.z, 0.f));
    hv.w = f2bf(fmaxf(pv.w + ev.w, 0.f));
    *(ushort4*)(&sA[t & 3][aw]) = hv;
  };

  // ---- prologue
  for (int i = tid; i < JH_; i += 512) sE[i] = eRow[i];
  stage(0, 0);
  float4 pbuild = *(const float4*)(pSrc);        // p(0)
  float4 pnext  = *(const float4*)(pSrc + 32);   // p(1)
  LGKM0;
  __builtin_amdgcn_s_barrier();                  // sE visible
  build(0, pbuild);
  pbuild = pnext;
  asm volatile("s_waitcnt vmcnt(0) lgkmcnt(0)" ::: "memory");
  __builtin_amdgcn_s_barrier();                  // A(0), B(0) ready

  for (int t = 0; t < KT_; t++) {
    if (t + 1 < KT_) stage(t + 1, (t + 1) & 1);
    float4 pfut;
    if (t + 2 < KT_) pfut = *(const float4*)(pSrc + (t + 2) * 32);
    if (t + 1 < KT_) { build(t + 1, pbuild); pbuild = pfut; }
    SCHEDB;
    if (t < KT_ - 2) { VMW(9); } else if (t == KT_ - 2) { VMW(8); } else { VMW(0); }
    SCHEDB;
    __builtin_amdgcn_s_barrier();
    const u16* Ab = &sA[t & 3][lk * 512];
    const u16* Bb = &sB[t & 1][lk * 8192 + wn * 1024];
    bf16x8 af[4], bq[8];
#pragma unroll
    for (int mf = 0; mf < 4; mf++)
      af[mf] = *(const bf16x8*)(Ab + (mf * 16 + lr) * 8);
#pragma unroll
    for (int nf = 0; nf < 8; nf++)
      bq[nf] = *(const bf16x8*)(Bb + (nf * 16 + lr) * 8);
    LGKM0; SCHEDB;
    __builtin_amdgcn_s_setprio(1);
#pragma unroll
    for (int mf = 0; mf < 4; mf++)
#pragma unroll
      for (int nf = 0; nf < 8; nf++)
        acc[mf][nf] = __builtin_amdgcn_mfma_f32_16x16x32_bf16(af[mf], bq[nf], acc[mf][nf], 0, 0, 0);
    __builtin_amdgcn_s_setprio(0);
  }

  // ---------------- epilogue: bias + log_softmax + fp32 store ----------------
  float bv[8];
#pragma unroll
  for (int nf = 0; nf < 8; nf++) bv[nf] = bout[wn * 128 + nf * 16 + lr];
#pragma unroll
  for (int mf = 0; mf < 4; mf++)
#pragma unroll
    for (int nf = 0; nf < 8; nf++)
#pragma unroll
      for (int r = 0; r < 4; r++)
        acc[mf][nf][r] += bv[nf];

  float gm[4][4];
#pragma unroll
  for (int mf = 0; mf < 4; mf++)
#pragma unroll
    for (int r = 0; r < 4; r++) {
      float m = acc[mf][0][r];
#pragma unroll
      for (int nf = 1; nf < 8; nf++) m = fmaxf(m, acc[mf][nf][r]);
#pragma unroll
      for (int o = 1; o < 16; o <<= 1) m = fmaxf(m, __shfl_xor(m, o, 64));
      gm[mf][r] = m;
    }
  if ((lane & 15) == 0) {
#pragma unroll
    for (int mf = 0; mf < 4; mf++)
#pragma unroll
      for (int r = 0; r < 4; r++)
        redm[(mf * 16 + lk * 4 + r) * 8 + wn] = gm[mf][r];
  }
  __syncthreads();
#pragma unroll
  for (int mf = 0; mf < 4; mf++)
#pragma unroll
    for (int r = 0; r < 4; r++) {
      int row = mf * 16 + lk * 4 + r;
      float m = redm[row * 8];
#pragma unroll
      for (int w = 1; w < 8; w++) m = fmaxf(m, redm[row * 8 + w]);
      gm[mf][r] = m;
    }
  float ls[4][4];
#pragma unroll
  for (int mf = 0; mf < 4; mf++)
#pragma unroll
    for (int r = 0; r < 4; r++) {
      float s = 0.f;
#pragma unroll
      for (int nf = 0; nf < 8; nf++) s += __expf(acc[mf][nf][r] - gm[mf][r]);
#pragma unroll
      for (int o = 1; o < 16; o <<= 1) s += __shfl_xor(s, o, 64);
      ls[mf][r] = s;
    }
  if ((lane & 15) == 0) {
#pragma unroll
    for (int mf = 0; mf < 4; mf++)
#pragma unroll
      for (int r = 0; r < 4; r++)
        reds[(mf * 16 + lk * 4 + r) * 8 + wn] = ls[mf][r];
  }
  __syncthreads();
#pragma unroll
  for (int mf = 0; mf < 4; mf++)
#pragma unroll
    for (int r = 0; r < 4; r++) {
      int row = mf * 16 + lk * 4 + r;
      float s = reds[row * 8];
#pragma unroll
      for (int w = 1; w < 8; w++) s += reds[row * 8 + w];
      ls[mf][r] = gm[mf][r] + __logf(s);
    }
#pragma unroll
  for (int mf = 0; mf < 4; mf++)
#pragma unroll
    for (int nf = 0; nf < 8; nf++)
#pragma unroll
      for (int r = 0; r < 4; r++)
        outB[(size_t)(mf * 16 + lk * 4 + r) * V_ + wn * 128 + nf * 16 + lr] =
            acc[mf][nf][r] - ls[mf][r];
}

// ---------------------------------------------------------------------------
extern "C" void kernel_launch(void* const* d_in, const int* in_sizes, int n_in,
                              void* d_out, int out_size, void* d_ws, size_t ws_size,
                              hipStream_t stream) {
  const float* enc    = (const float*)d_in[0];
  const float* dec    = (const float*)d_in[1];
  const float* W_enc  = (const float*)d_in[2];
  const float* b_enc  = (const float*)d_in[3];
  const float* W_pred = (const float*)d_in[4];
  const float* b_pred = (const float*)d_in[5];
  const float* W_out  = (const float*)d_in[6];
  const float* b_out  = (const float*)d_in[7];
  float* out = (float*)d_out;

  char* ws = (char*)d_ws;
  size_t off = 0;
  auto alloc = [&](size_t bytes) {
    void* pp = ws + off;
    off = (off + bytes + 255) & ~(size_t)255;
    return pp;
  };
  u16* encT   = (u16*)alloc((size_t)B_ * T_ * EH_ * 2);
  u16* decT   = (u16*)alloc((size_t)B_ * U_ * PH_ * 2);
  u16* WencB  = (u16*)alloc((size_t)JH_ * EH_ * 2);
  u16* WpredB = (u16*)alloc((size_t)JH_ * PH_ * 2);
  u16* Wpk    = (u16*)alloc((size_t)KT_ * 32768 * 2);
  float* eBuf = (float*)alloc((size_t)B_ * T_ * JH_ * 4);
  float* pBuf = (float*)alloc((size_t)B_ * U_ * JH_ * 4);

  // front-end
  k_transpose_cvt<<<dim3(T_ / 32, EH_ / 32, B_), 256, 0, stream>>>(enc, encT, EH_, T_);
  k_transpose_cvt<<<dim3(U_ / 32, PH_ / 32, B_), 256, 0, stream>>>(dec, decT, PH_, U_);
  k_prep_w<<<1360, 256, 0, stream>>>(W_enc, W_pred, W_out, WencB, WpredB, Wpk);
  k_proj_gemm<<<dim3(T_ / 64, JH_ / 64, B_), 256, 0, stream>>>(
      encT, WencB, b_enc, eBuf, EH_, JH_, (size_t)T_ * EH_, (size_t)T_ * JH_);
  k_proj_gemm<<<dim3(U_ / 64, JH_ / 64, B_), 256, 0, stream>>>(
      decT, WpredB, b_pred, pBuf, PH_, JH_, (size_t)U_ * PH_, (size_t)U_ * JH_);

  // fused joint GEMM + log_softmax: one block per 64 output rows
  k_fused<<<B_ * T_ * 2, 512, 0, stream>>>(eBuf, pBuf, Wpk, b_out, out);
}